// Round 2
// baseline (854.583 us; speedup 1.0000x reference)
//
#include <hip/hip_runtime.h>

#define NN 100000
#define NNP 100096   // NN padded to multiple of 128 (GEMM tail reads)
#define NE 600000
#define KE 3
#define NL 3
#define D  128
#define EPS 1e-5f
#define NB 391       // ceil(NN/256) blocks per etype for the scan
#define NBKT 196     // buckets per etype: dst>>9 (512 nodes/bucket)
#define EPB 4096     // edges per block in bucket passes
#define NEB 147      // ceil(NE/EPB)
#define NSL 16       // stat slices (atomic contention spread)

typedef __attribute__((ext_vector_type(8))) short short8;
typedef __attribute__((ext_vector_type(4))) float floatx4;

__device__ __forceinline__ void atomic_add_f32(float* p, float v) { unsafeAtomicAdd(p, v); }

__device__ __forceinline__ float bf2f(unsigned int u16) {
    unsigned int v = u16 << 16;
    return __builtin_bit_cast(float, v);
}
__device__ __forceinline__ unsigned int f2bf(float f) {   // RNE
    unsigned int u = __builtin_bit_cast(unsigned int, f);
    u += 0x7FFFu + ((u >> 16) & 1u);
    return u >> 16;
}
__device__ __forceinline__ unsigned int pack2(float a, float b) {
    return f2bf(a) | (f2bf(b) << 16);
}

// async global->LDS, 16B per lane; LDS dest = wave-uniform base + lane*16
__device__ __forceinline__ void gload16(const void* g, void* l) {
    __builtin_amdgcn_global_load_lds(
        (const __attribute__((address_space(1))) void*)g,
        (__attribute__((address_space(3))) void*)l, 16, 0, 0);
}

// ---- x (fp32) -> h (bf16) ----
__global__ void convert_x_kernel(const float* __restrict__ x, ushort* __restrict__ hbf) {
    size_t i = (size_t)blockIdx.x * blockDim.x + threadIdx.x;
    if (i >= (size_t)NN * D / 4) return;
    float4 v = *(const float4*)(x + i * 4);
    uint2 o;
    o.x = pack2(v.x, v.y);
    o.y = pack2(v.z, v.w);
    *(uint2*)(hbf + i * 4) = o;
}

// ---- W prep: Bt[l,k][n][kk] bf16 ----
__global__ void wprep_kernel(const float* __restrict__ Ws, const float* __restrict__ Wn,
                             ushort* __restrict__ Bt) {
    int idx = blockIdx.x * blockDim.x + threadIdx.x;
    if (idx >= NL * KE * 128 * 256) return;
    int lk  = idx >> 15;
    int rem = idx & 32767;
    int n   = rem >> 8;
    int kk  = rem & 255;
    float v = (kk < 128) ? Ws[(size_t)lk * 16384 + kk * 128 + n]
                         : Wn[(size_t)lk * 16384 + (kk - 128) * 128 + n];
    Bt[idx] = (ushort)f2bf(v);
}

// ---- BN fold for layer l>=1: Bt_self' = diag(sc)*Ws, bias' = b + sh@Ws ----
__global__ void fold_kernel(const float* __restrict__ Wsl, const float* __restrict__ bsrc,
                            const float* __restrict__ ssl, ushort* __restrict__ Btl,
                            float* __restrict__ biasW) {
    const int k = blockIdx.x;      // KE
    const int n = threadIdx.x;     // 128
    const float* W = Wsl + (size_t)k * D * D;
    ushort* B = Btl + (size_t)k * 32768;
    float acc = 0.f;
    #pragma unroll 4
    for (int kk = 0; kk < D; ++kk) {
        float w = W[kk * D + n];
        acc += ssl[D + kk] * w;
        B[n * 256 + kk] = (ushort)f2bf(ssl[kk] * w);
    }
    biasW[k * D + n] = bsrc[k * D + n] + acc;
}

// ==== CSR build: two-level bucket sort ====
__global__ void bucket_count_kernel(const int* __restrict__ dst,
                                    int* __restrict__ bucketTotal, int* __restrict__ blockBase) {
    const int blk = blockIdx.x;               // KE*NEB
    const int k = blk / NEB, cb = blk - k * NEB;
    __shared__ int hist[NBKT];
    for (int i = threadIdx.x; i < NBKT; i += 256) hist[i] = 0;
    __syncthreads();
    const int e0 = cb * EPB, e1 = min(e0 + EPB, NE);
    for (int e = e0 + threadIdx.x; e < e1; e += 256)
        atomicAdd(&hist[dst[(size_t)k * NE + e] >> 9], 1);
    __syncthreads();
    for (int i = threadIdx.x; i < NBKT; i += 256) {
        int c = hist[i];
        int base = c ? atomicAdd(&bucketTotal[k * NBKT + i], c) : 0;
        blockBase[(size_t)blk * NBKT + i] = base;
    }
}

__global__ void bucket_scan_kernel(const int* __restrict__ bucketTotal,
                                   int* __restrict__ bucketStart) {
    __shared__ int sd[1024];
    const int t = threadIdx.x;
    int v = (t < KE * NBKT) ? bucketTotal[t] : 0;
    sd[t] = v;
    __syncthreads();
    for (int off = 1; off < 1024; off <<= 1) {
        int u = (t >= off) ? sd[t - off] : 0;
        __syncthreads();
        sd[t] += u;
        __syncthreads();
    }
    if (t < KE * NBKT) bucketStart[t] = sd[t] - v;
}

__global__ void bucket_scatter_kernel(const int* __restrict__ src, const int* __restrict__ dst,
                                      const int* __restrict__ bucketStart,
                                      const int* __restrict__ blockBase,
                                      uint2* __restrict__ ebuf) {
    const int blk = blockIdx.x;
    const int k = blk / NEB, cb = blk - k * NEB;
    __shared__ int hist[NBKT], binoff[NBKT], cur[NBKT];
    __shared__ int sc[256];
    __shared__ uint2 stage[EPB];
    const int t = threadIdx.x;
    for (int i = t; i < NBKT; i += 256) hist[i] = 0;
    __syncthreads();
    const int e0 = cb * EPB, e1 = min(e0 + EPB, NE);
    for (int e = e0 + t; e < e1; e += 256)
        atomicAdd(&hist[dst[(size_t)k * NE + e] >> 9], 1);
    __syncthreads();
    int hv = (t < NBKT) ? hist[t] : 0;
    sc[t] = hv;
    __syncthreads();
    for (int off = 1; off < 256; off <<= 1) {
        int u = (t >= off) ? sc[t - off] : 0;
        __syncthreads();
        sc[t] += u;
        __syncthreads();
    }
    if (t < NBKT) { binoff[t] = sc[t] - hv; cur[t] = sc[t] - hv; }
    __syncthreads();
    for (int e = e0 + t; e < e1; e += 256) {
        int d = dst[(size_t)k * NE + e], s = src[(size_t)k * NE + e];
        int b = d >> 9;
        int p = atomicAdd(&cur[b], 1);
        stage[p] = make_uint2((unsigned)s, (unsigned)d);
    }
    __syncthreads();
    const int n = e1 - e0;
    for (int i = t; i < n; i += 256) {
        uint2 ed = stage[i];
        int b = (int)(ed.y >> 9);
        int pos = bucketStart[k * NBKT + b] + blockBase[(size_t)blk * NBKT + b] + (i - binoff[b]);
        ebuf[pos] = ed;
    }
}

__global__ void bucket_deg_kernel(const uint2* __restrict__ ebuf,
                                  const int* __restrict__ bucketStart, int* __restrict__ degi) {
    const int blk = blockIdx.x;               // KE*NBKT
    const int k = blk / NBKT, b = blk - k * NBKT;
    __shared__ int cnt[512];
    for (int i = threadIdx.x; i < 512; i += 256) cnt[i] = 0;
    __syncthreads();
    const int s0 = bucketStart[blk];
    const int s1 = (blk + 1 < KE * NBKT) ? bucketStart[blk + 1] : KE * NE;
    for (int e = s0 + threadIdx.x; e < s1; e += 256)
        atomicAdd(&cnt[ebuf[e].y & 511], 1);
    __syncthreads();
    const int n0 = b << 9;
    for (int i = threadIdx.x; i < 512; i += 256) {
        int node = n0 + i;
        if (node < NN) degi[(size_t)k * NN + node] = cnt[i];
    }
}

__global__ void scan_a_kernel(const int* __restrict__ degi, int* __restrict__ bsum) {
    const int b = blockIdx.x;
    const int k = b / NB, lb = b - k * NB;
    const int t = threadIdx.x;
    const int i = lb * 256 + t;
    int deg = (i < NN) ? degi[(size_t)k * NN + i] : 0;
    __shared__ int sd[256];
    sd[t] = deg;
    __syncthreads();
    for (int off = 128; off > 0; off >>= 1) {
        if (t < off) sd[t] += sd[t + off];
        __syncthreads();
    }
    if (t == 0) bsum[b] = sd[0];
}

__global__ void scan_b_kernel(int* __restrict__ bsum) {
    const int k = blockIdx.x;
    const int t = threadIdx.x;          // 512
    int v = (t < NB) ? bsum[k * NB + t] : 0;
    __shared__ int sd[512];
    sd[t] = v;
    __syncthreads();
    for (int off = 1; off < 512; off <<= 1) {
        int u = (t >= off) ? sd[t - off] : 0;
        __syncthreads();
        sd[t] += u;
        __syncthreads();
    }
    if (t < NB) bsum[k * NB + t] = sd[t] - v;
}

__global__ void scan_c_kernel(const int* __restrict__ degi, const int* __restrict__ bsum,
                              int* __restrict__ rowptr, float* __restrict__ invdeg) {
    const int b = blockIdx.x;
    const int k = b / NB, lb = b - k * NB;
    const int t = threadIdx.x;
    const int i = lb * 256 + t;
    int deg = (i < NN) ? degi[(size_t)k * NN + i] : 0;
    __shared__ int sd[256];
    sd[t] = deg;
    __syncthreads();
    for (int off = 1; off < 256; off <<= 1) {
        int u = (t >= off) ? sd[t - off] : 0;
        __syncthreads();
        sd[t] += u;
        __syncthreads();
    }
    int val = bsum[b] + sd[t] - deg;
    if (i < NN) {
        rowptr[(size_t)k * (NN + 1) + i] = val;
        invdeg[(size_t)k * NN + i] = 1.0f / (float)max(deg, 1);
    }
    if (i == NN) rowptr[(size_t)k * (NN + 1) + NN] = NE;
}

__global__ void bucket_fill_kernel(const uint2* __restrict__ ebuf,
                                   const int* __restrict__ bucketStart,
                                   const int* __restrict__ rowptr, int* __restrict__ csr) {
    const int blk = blockIdx.x;
    const int k = blk / NBKT, b = blk - k * NBKT;
    __shared__ int cur[512];
    const int n0 = b << 9;
    for (int i = threadIdx.x; i < 512; i += 256) {
        int node = n0 + i;
        cur[i] = (node < NN) ? rowptr[(size_t)k * (NN + 1) + node] : 0;
    }
    __syncthreads();
    const int s0 = bucketStart[blk];
    const int s1 = (blk + 1 < KE * NBKT) ? bucketStart[blk + 1] : KE * NE;
    for (int e = s0 + threadIdx.x; e < s1; e += 256) {
        uint2 ed = ebuf[e];
        int p = atomicAdd(&cur[ed.y & 511], 1);
        csr[(size_t)k * NE + p] = (int)ed.x;
    }
}

// ==== fused layer: per-block gather+aggregate (neigh A tile in LDS) + GEMM + stats ====
// LDS swizzle convention (both-sides, rule #21): within each [128][64]-ushort subtile,
// stored col-chunk c (16B) of row r holds global chunk c ^ (r&7); readers XOR the same.
__global__ __launch_bounds__(256, 2)
void layer_fused_kernel(const ushort* __restrict__ hprev,
                        const int* __restrict__ csr, const int* __restrict__ rowptr,
                        const float* __restrict__ invdeg,
                        const ushort* __restrict__ Bt,     // [KE][128n][256kk]
                        const float* __restrict__ bias,    // [KE][D]
                        const float* __restrict__ ssl,     // prev-layer BN affine
                        int affine, int relu,
                        ushort* __restrict__ hnext,
                        float* __restrict__ colsum, float* __restrict__ colsq) {
    __shared__ __align__(16) ushort Asf[2][128][64];   // 32 KB self-A (persistent, kc-split)
    __shared__ __align__(16) ushort Anb[2][128][64];   // 32 KB neigh-A (rebuilt per etype)
    __shared__ __align__(16) ushort Bst[128][64];      // 16 KB B chunk (per part/kc)
    const int tid  = threadIdx.x;
    const int wave = tid >> 6, lane = tid & 63;
    const int wm = wave & 1, wn = wave >> 1;
    const int lrow = lane & 15, quad = lane >> 4;
    const int m0 = blockIdx.x * 128;
    // staging geometry (gload16): lane -> row = w*32+i*8+(lane>>3), col chunk = lane&7
    const int srow  = lane >> 3;
    const int scolb = ((lane & 7) ^ srow) << 4;        // pre-swizzled source col byte
    // gather geometry: 16 lanes/row
    const int grp = tid >> 4, l16 = tid & 15;
    const int qb  = l16 * 8;                           // ushort offset in source row
    const int gkc = l16 >> 3, gc3 = l16 & 7;           // dest subtile / chunk

    // ---- stage self A tile once (reused for all 3 etypes) ----
    {
        const char* Ab = (const char*)hprev + (size_t)m0 * 256;
        #pragma unroll
        for (int kc = 0; kc < 2; ++kc)
            #pragma unroll
            for (int i = 0; i < 4; ++i)
                gload16(Ab + (size_t)(wave * 32 + i * 8 + srow) * 256 + kc * 128 + scolb,
                        (char*)Asf + kc * 16384 + wave * 4096 + i * 1024);
    }

    float4 ac0, ac1, ah0, ah1;
    if (affine) {
        ac0 = *(const float4*)(ssl + qb);
        ac1 = *(const float4*)(ssl + qb + 4);
        ah0 = *(const float4*)(ssl + D + qb);
        ah1 = *(const float4*)(ssl + D + qb + 4);
    } else {
        ac0 = make_float4(1.f, 1.f, 1.f, 1.f); ac1 = ac0;
        ah0 = make_float4(0.f, 0.f, 0.f, 0.f); ah1 = ah0;
    }

    floatx4 tot[4][4];
    #pragma unroll
    for (int a = 0; a < 4; ++a)
        #pragma unroll
        for (int b = 0; b < 4; ++b)
            tot[a][b] = (floatx4){0.f, 0.f, 0.f, 0.f};

    for (int k = 0; k < KE; ++k) {
        const char* Btk = (const char*)Bt + (size_t)k * 65536;   // 128 n-rows * 512 B
        __syncthreads();                       // prior Bst/Anb reads complete
        // prefetch first B chunk (part0,kc0)
        #pragma unroll
        for (int i = 0; i < 4; ++i)
            gload16(Btk + (size_t)(wave * 32 + i * 8 + srow) * 512 + scolb,
                    (char*)Bst + wave * 4096 + i * 1024);

        // ---- gather+aggregate neigh tile for this block's 128 rows ----
        const int* cs = csr + (size_t)k * NE;
        #pragma unroll 1
        for (int pass = 0; pass < 8; ++pass) {
            int row  = pass * 16 + grp;
            int node = m0 + row;
            float f0=0,f1=0,f2=0,f3=0,f4=0,f5=0,f6=0,f7=0;
            float iv = 0.f, mk = 0.f;
            if (node < NN) {
                const int* rp = rowptr + (size_t)k * (NN + 1) + node;
                int beg = rp[0], end = rp[1];
                int j = beg;
                for (; j + 4 <= end; j += 4) {
                    int s0 = cs[j], s1 = cs[j + 1], s2 = cs[j + 2], s3 = cs[j + 3];
                    uint4 a = *(const uint4*)(hprev + (size_t)s0 * D + qb);
                    uint4 b = *(const uint4*)(hprev + (size_t)s1 * D + qb);
                    uint4 c = *(const uint4*)(hprev + (size_t)s2 * D + qb);
                    uint4 d = *(const uint4*)(hprev + (size_t)s3 * D + qb);
                    f0 += bf2f(a.x & 0xffff) + bf2f(b.x & 0xffff) + bf2f(c.x & 0xffff) + bf2f(d.x & 0xffff);
                    f1 += bf2f(a.x >> 16)    + bf2f(b.x >> 16)    + bf2f(c.x >> 16)    + bf2f(d.x >> 16);
                    f2 += bf2f(a.y & 0xffff) + bf2f(b.y & 0xffff) + bf2f(c.y & 0xffff) + bf2f(d.y & 0xffff);
                    f3 += bf2f(a.y >> 16)    + bf2f(b.y >> 16)    + bf2f(c.y >> 16)    + bf2f(d.y >> 16);
                    f4 += bf2f(a.z & 0xffff) + bf2f(b.z & 0xffff) + bf2f(c.z & 0xffff) + bf2f(d.z & 0xffff);
                    f5 += bf2f(a.z >> 16)    + bf2f(b.z >> 16)    + bf2f(c.z >> 16)    + bf2f(d.z >> 16);
                    f6 += bf2f(a.w & 0xffff) + bf2f(b.w & 0xffff) + bf2f(c.w & 0xffff) + bf2f(d.w & 0xffff);
                    f7 += bf2f(a.w >> 16)    + bf2f(b.w >> 16)    + bf2f(c.w >> 16)    + bf2f(d.w >> 16);
                }
                for (; j < end; ++j) {
                    int s0 = cs[j];
                    uint4 a = *(const uint4*)(hprev + (size_t)s0 * D + qb);
                    f0 += bf2f(a.x & 0xffff); f1 += bf2f(a.x >> 16);
                    f2 += bf2f(a.y & 0xffff); f3 += bf2f(a.y >> 16);
                    f4 += bf2f(a.z & 0xffff); f5 += bf2f(a.z >> 16);
                    f6 += bf2f(a.w & 0xffff); f7 += bf2f(a.w >> 16);
                }
                iv = invdeg[(size_t)k * NN + node];
                if (end > beg) mk = 1.f;
            }
            float r0 = f0 * iv * ac0.x + mk * ah0.x;
            float r1 = f1 * iv * ac0.y + mk * ah0.y;
            float r2 = f2 * iv * ac0.z + mk * ah0.z;
            float r3 = f3 * iv * ac0.w + mk * ah0.w;
            float r4 = f4 * iv * ac1.x + mk * ah1.x;
            float r5 = f5 * iv * ac1.y + mk * ah1.y;
            float r6 = f6 * iv * ac1.z + mk * ah1.z;
            float r7 = f7 * iv * ac1.w + mk * ah1.w;
            uint4 o;
            o.x = pack2(r0, r1);
            o.y = pack2(r2, r3);
            o.z = pack2(r4, r5);
            o.w = pack2(r6, r7);
            *(uint4*)((char*)Anb + gkc * 16384 + row * 128 + ((gc3 ^ (row & 7)) << 4)) = o;
        }

        // ---- MFMA: 4 chunks (self kc0, self kc1, neigh kc0, neigh kc1) ----
        floatx4 o4[4][4];
        #pragma unroll
        for (int a = 0; a < 4; ++a)
            #pragma unroll
            for (int b = 0; b < 4; ++b)
                o4[a][b] = (floatx4){0.f, 0.f, 0.f, 0.f};
        #pragma unroll
        for (int idx = 0; idx < 4; ++idx) {
            __syncthreads();                   // Bst gloads + (idx0) Anb ds_writes visible
            const char* Ab = (idx >> 1) ? (const char*)Anb : (const char*)Asf;
            const int kcoff = (idx & 1) * 16384;
            #pragma unroll
            for (int ks = 0; ks < 2; ++ks) {
                short8 af[4], bfr[4];
                const int cb = ks * 64 + quad * 16;
                #pragma unroll
                for (int im = 0; im < 4; ++im) {
                    int ra = wm * 64 + im * 16 + lrow;
                    af[im] = *(const short8*)(Ab + kcoff + ra * 128 + (cb ^ ((ra & 7) << 4)));
                }
                #pragma unroll
                for (int in = 0; in < 4; ++in) {
                    int rb = wn * 64 + in * 16 + lrow;
                    bfr[in] = *(const short8*)((const char*)Bst + rb * 128 + (cb ^ ((rb & 7) << 4)));
                }
                #pragma unroll
                for (int im = 0; im < 4; ++im)
                    #pragma unroll
                    for (int in = 0; in < 4; ++in)
                        o4[im][in] = __builtin_amdgcn_mfma_f32_16x16x32_bf16(
                            af[im], bfr[in], o4[im][in], 0, 0, 0);
            }
            if (idx < 3) {
                __syncthreads();               // Bst reads done -> restage
                const int p2 = (idx + 1) >> 1, k2 = (idx + 1) & 1;
                #pragma unroll
                for (int i = 0; i < 4; ++i)
                    gload16(Btk + (size_t)(wave * 32 + i * 8 + srow) * 512 + p2 * 256 + k2 * 128 + scolb,
                            (char*)Bst + wave * 4096 + i * 1024);
            }
        }
        const float* bk = bias + k * D;
        float bv[4];
        #pragma unroll
        for (int in = 0; in < 4; ++in) bv[in] = bk[wn * 64 + in * 16 + lrow];
        #pragma unroll
        for (int im = 0; im < 4; ++im)
            #pragma unroll
            for (int in = 0; in < 4; ++in)
                #pragma unroll
                for (int r = 0; r < 4; ++r) {
                    float v = o4[im][in][r] + bv[in];
                    if (relu) v = fmaxf(v, 0.f);
                    tot[im][in][r] += v;
                }
    }

    // ---- fused column stats (mask tail rows >= NN) ----
    float ls[4] = {0.f, 0.f, 0.f, 0.f}, lq[4] = {0.f, 0.f, 0.f, 0.f};
    #pragma unroll
    for (int im = 0; im < 4; ++im)
        #pragma unroll
        for (int r = 0; r < 4; ++r) {
            int row = m0 + wm * 64 + im * 16 + quad * 4 + r;
            bool ok = row < NN;
            #pragma unroll
            for (int in = 0; in < 4; ++in) {
                float v = ok ? tot[im][in][r] : 0.f;
                ls[in] += v;
                lq[in] += v * v;
            }
        }
    __syncthreads();                                   // all MFMA LDS reads done
    float* redS = (float*)&Anb[0][0][0];               // [128][8] floats (in Anb)
    float* redQ = redS + 1024;
    #pragma unroll
    for (int in = 0; in < 4; ++in) {
        int col = wn * 64 + in * 16 + lrow;
        int slot = col * 8 + wm * 4 + quad;
        redS[slot] = ls[in];
        redQ[slot] = lq[in];
    }
    __syncthreads();
    if (tid < 128) {
        float s = 0.f, q = 0.f;
        #pragma unroll
        for (int i = 0; i < 8; ++i) { s += redS[tid * 8 + i]; q += redQ[tid * 8 + i]; }
        int slice = blockIdx.x & (NSL - 1);
        atomic_add_f32(&colsum[slice * D + tid], s);
        atomic_add_f32(&colsq[slice * D + tid], q);
    }

    // ---- C tile -> LDS (bf16, in Asf region) -> coalesced global stores ----
    ushort* Cs = &Asf[0][0][0];                        // [128][128] ushort = 32 KB
    #pragma unroll
    for (int im = 0; im < 4; ++im)
        #pragma unroll
        for (int r = 0; r < 4; ++r) {
            int rl = wm * 64 + im * 16 + quad * 4 + r;
            #pragma unroll
            for (int in = 0; in < 4; ++in)
                Cs[rl * 128 + wn * 64 + in * 16 + lrow] = (ushort)f2bf(tot[im][in][r]);
        }
    __syncthreads();
    #pragma unroll
    for (int jj = 0; jj < 8; ++jj) {
        int c8 = tid + jj * 256;           // uint4 index
        int rl = c8 >> 4;                  // 16 uint4 per 128-col row
        int cc = (c8 & 15) * 8;
        int row = m0 + rl;
        if (row < NN)
            *(uint4*)(hnext + (size_t)row * D + cc) = *(const uint4*)(Cs + rl * 128 + cc);
    }
}

// ---- batchnorm finalize (also re-zeros stats for the next layer) ----
__global__ void finalize_kernel(float* __restrict__ colsum, float* __restrict__ colsq,
                                const float* __restrict__ gamma, const float* __restrict__ beta,
                                float* __restrict__ ssl) {
    int c = threadIdx.x;  // 128
    float s = 0.f, q = 0.f;
    #pragma unroll
    for (int i = 0; i < NSL; ++i) { s += colsum[i * D + c]; q += colsq[i * D + c]; }
    float mu  = s * (1.0f / NN);
    float var = q * (1.0f / NN) - mu * mu;
    float sc  = gamma[c] * rsqrtf(var + EPS);
    ssl[c]     = sc;
    ssl[D + c] = beta[c] - mu * sc;
    #pragma unroll
    for (int i = 0; i < NSL; ++i) { colsum[i * D + c] = 0.f; colsq[i * D + c] = 0.f; }
}

// ---- final BN apply (fp32 out), only for the last layer ----
__global__ void bn_kernel(const ushort* __restrict__ accb, const float* __restrict__ ssl,
                          float* __restrict__ out) {
    size_t i = (size_t)blockIdx.x * blockDim.x + threadIdx.x;
    if (i >= (size_t)NN * D / 4) return;
    int c4 = (int)(i & 31) << 2;
    uint2 a = *(const uint2*)(accb + i * 4);
    float4 v = {bf2f(a.x & 0xffff), bf2f(a.x >> 16), bf2f(a.y & 0xffff), bf2f(a.y >> 16)};
    float4 sc = *(const float4*)(ssl + c4);
    float4 sh = *(const float4*)(ssl + D + c4);
    float4 o;
    o.x = v.x * sc.x + sh.x;
    o.y = v.y * sc.y + sh.y;
    o.z = v.z * sc.z + sh.z;
    o.w = v.w * sc.w + sh.w;
    *(float4*)(out + i * 4) = o;
}

extern "C" void kernel_launch(void* const* d_in, const int* in_sizes, int n_in,
                              void* d_out, int out_size, void* d_ws, size_t ws_size,
                              hipStream_t stream) {
    const float* x       = (const float*)d_in[0];
    const int*   src     = (const int*)d_in[1];
    const int*   dst     = (const int*)d_in[2];
    const float* W_self  = (const float*)d_in[3];
    const float* W_neigh = (const float*)d_in[4];
    const float* bvec    = (const float*)d_in[5];
    const float* gamma   = (const float*)d_in[6];
    const float* beta    = (const float*)d_in[7];
    float* out = (float*)d_out;

    // ---- workspace layout ----
    ushort* accb   = (ushort*)d_ws;                       // NNP*D bf16 (ping buffer)
    float*  invdeg = (float*)(accb + (size_t)NNP * D);    // KE*NN
    float*  colsum = invdeg + (size_t)KE * NN;            // NSL*D
    float*  colsq  = colsum + NSL * D;                    // NSL*D
    float*  ss     = colsq + NSL * D;                     // NL*2*D (per-layer BN affine)
    float*  biasW  = ss + NL * 2 * D;                     // KE*D (folded bias)
    ushort* hbf    = (ushort*)(biasW + KE * D);           // NNP*D bf16 (pong buffer)
    ushort* Btw    = hbf + (size_t)NNP * D;               // NL*KE*128*256 bf16
    int*    degi   = (int*)(Btw + (size_t)NL * KE * 128 * 256);  // KE*NN
    int*    rowptr = degi + (size_t)KE * NN;              // KE*(NN+1)
    int*    csr    = rowptr + (size_t)KE * (NN + 1);      // KE*NE
    int*    bsum   = csr + (size_t)KE * NE;               // KE*NB
    int*    bucketTotal = bsum + (size_t)KE * NB;         // KE*NBKT
    int*    bucketStart = bucketTotal + KE * NBKT;        // KE*NBKT
    int*    blockBase   = bucketStart + KE * NBKT;        // KE*NEB*NBKT
    uint2*  ebuf   = (uint2*)accb;  // aliases accb (14.4MB <= 25.6MB); CSR build precedes layer loop

    convert_x_kernel<<<(int)(((size_t)NN * D / 4 + 255) / 256), 256, 0, stream>>>(x, hbf);
    wprep_kernel<<<(NL * KE * 128 * 256 + 255) / 256, 256, 0, stream>>>(W_self, W_neigh, Btw);
    hipMemsetAsync(colsum, 0, sizeof(float) * 2 * NSL * D, stream);

    hipMemsetAsync(bucketTotal, 0, sizeof(int) * KE * NBKT, stream);
    bucket_count_kernel<<<KE * NEB, 256, 0, stream>>>(dst, bucketTotal, blockBase);
    bucket_scan_kernel<<<1, 1024, 0, stream>>>(bucketTotal, bucketStart);
    bucket_scatter_kernel<<<KE * NEB, 256, 0, stream>>>(src, dst, bucketStart, blockBase, ebuf);
    bucket_deg_kernel<<<KE * NBKT, 256, 0, stream>>>(ebuf, bucketStart, degi);
    scan_a_kernel<<<KE * NB, 256, 0, stream>>>(degi, bsum);
    scan_b_kernel<<<KE, 512, 0, stream>>>(bsum);
    scan_c_kernel<<<KE * NB, 256, 0, stream>>>(degi, bsum, rowptr, invdeg);
    bucket_fill_kernel<<<KE * NBKT, 256, 0, stream>>>(ebuf, bucketStart, rowptr, csr);

    for (int l = 0; l < NL; ++l) {
        int relu = (l < NL - 1) ? 1 : 0;
        const ushort* hprev = (l & 1) ? accb : hbf;   // l0: hbf->accb, l1: accb->hbf, l2: hbf->accb
        ushort*       hnext = (l & 1) ? hbf : accb;
        layer_fused_kernel<<<NNP / 128, 256, 0, stream>>>(
            hprev, csr, rowptr, invdeg,
            Btw + (size_t)l * KE * 128 * 256,
            (l == 0) ? bvec : biasW,
            ss + (size_t)(l ? l - 1 : 0) * 2 * D, l > 0, relu,
            hnext, colsum, colsq);
        finalize_kernel<<<1, 128, 0, stream>>>(colsum, colsq, gamma + (size_t)l * D,
                                               beta + (size_t)l * D, ss + (size_t)l * 2 * D);
        if (l + 1 < NL)
            fold_kernel<<<KE, 128, 0, stream>>>(
                W_self + (size_t)(l + 1) * KE * D * D,
                bvec + (size_t)(l + 1) * KE * D,
                ss + (size_t)l * 2 * D,
                Btw + (size_t)(l + 1) * KE * 128 * 256,
                biasW);
    }
    bn_kernel<<<(int)(((size_t)NN * D / 4 + 255) / 256), 256, 0, stream>>>(
        accb, ss + (size_t)(NL - 1) * 2 * D, out);
}

// Round 5
// 587.288 us; speedup vs baseline: 1.4551x; 1.4551x over previous
//
#include <hip/hip_runtime.h>

#define NN 100000
#define NNP 100096   // NN padded to multiple of 128 (GEMM tail reads)
#define NE 600000
#define KE 3
#define NL 3
#define D  128
#define EPS 1e-5f
#define NB 391       // ceil(NN/256) blocks per etype for the scan
#define NBKT 196     // buckets per etype: dst>>9 (512 nodes/bucket)
#define EPB 4096     // edges per block in bucket passes
#define NEB 147      // ceil(NE/EPB)
#define NSL 16       // stat slices (atomic contention spread)

typedef __attribute__((ext_vector_type(8))) short short8;
typedef __attribute__((ext_vector_type(4))) float floatx4;

__device__ __forceinline__ void atomic_add_f32(float* p, float v) { unsafeAtomicAdd(p, v); }

__device__ __forceinline__ float bf2f(unsigned int u16) {
    unsigned int v = u16 << 16;
    return __builtin_bit_cast(float, v);
}
__device__ __forceinline__ unsigned int f2bf(float f) {   // RNE
    unsigned int u = __builtin_bit_cast(unsigned int, f);
    u += 0x7FFFu + ((u >> 16) & 1u);
    return u >> 16;
}
__device__ __forceinline__ unsigned int pack2(float a, float b) {
    return f2bf(a) | (f2bf(b) << 16);
}

// async global->LDS, 16B per lane; LDS dest = wave-uniform base + lane*16
__device__ __forceinline__ void gload16(const void* g, void* l) {
    __builtin_amdgcn_global_load_lds(
        (const __attribute__((address_space(1))) void*)g,
        (__attribute__((address_space(3))) void*)l, 16, 0, 0);
}

// ---- x (fp32) -> h (bf16) ----
__global__ void convert_x_kernel(const float* __restrict__ x, ushort* __restrict__ hbf) {
    size_t i = (size_t)blockIdx.x * blockDim.x + threadIdx.x;
    if (i >= (size_t)NN * D / 4) return;
    float4 v = *(const float4*)(x + i * 4);
    uint2 o;
    o.x = pack2(v.x, v.y);
    o.y = pack2(v.z, v.w);
    *(uint2*)(hbf + i * 4) = o;
}

// ---- W prep: Bt[l,k][n][kk] bf16 ----
__global__ void wprep_kernel(const float* __restrict__ Ws, const float* __restrict__ Wn,
                             ushort* __restrict__ Bt) {
    int idx = blockIdx.x * blockDim.x + threadIdx.x;
    if (idx >= NL * KE * 128 * 256) return;
    int lk  = idx >> 15;
    int rem = idx & 32767;
    int n   = rem >> 8;
    int kk  = rem & 255;
    float v = (kk < 128) ? Ws[(size_t)lk * 16384 + kk * 128 + n]
                         : Wn[(size_t)lk * 16384 + (kk - 128) * 128 + n];
    Bt[idx] = (ushort)f2bf(v);
}

// ---- BN fold for layer l>=1: Bt_self' = diag(sc)*Ws, bias' = b + sh@Ws ----
__global__ void fold_kernel(const float* __restrict__ Wsl, const float* __restrict__ bsrc,
                            const float* __restrict__ ssl, ushort* __restrict__ Btl,
                            float* __restrict__ biasW) {
    const int k = blockIdx.x;      // KE
    const int n = threadIdx.x;     // 128
    const float* W = Wsl + (size_t)k * D * D;
    ushort* B = Btl + (size_t)k * 32768;
    float acc = 0.f;
    #pragma unroll 4
    for (int kk = 0; kk < D; ++kk) {
        float w = W[kk * D + n];
        acc += ssl[D + kk] * w;
        B[n * 256 + kk] = (ushort)f2bf(ssl[kk] * w);
    }
    biasW[k * D + n] = bsrc[k * D + n] + acc;
}

// ==== CSR build: two-level bucket sort ====
__global__ void bucket_count_kernel(const int* __restrict__ dst,
                                    int* __restrict__ bucketTotal, int* __restrict__ blockBase) {
    const int blk = blockIdx.x;               // KE*NEB
    const int k = blk / NEB, cb = blk - k * NEB;
    __shared__ int hist[NBKT];
    for (int i = threadIdx.x; i < NBKT; i += 256) hist[i] = 0;
    __syncthreads();
    const int e0 = cb * EPB, e1 = min(e0 + EPB, NE);
    for (int e = e0 + threadIdx.x; e < e1; e += 256)
        atomicAdd(&hist[dst[(size_t)k * NE + e] >> 9], 1);
    __syncthreads();
    for (int i = threadIdx.x; i < NBKT; i += 256) {
        int c = hist[i];
        int base = c ? atomicAdd(&bucketTotal[k * NBKT + i], c) : 0;
        blockBase[(size_t)blk * NBKT + i] = base;
    }
}

__global__ void bucket_scan_kernel(const int* __restrict__ bucketTotal,
                                   int* __restrict__ bucketStart) {
    __shared__ int sd[1024];
    const int t = threadIdx.x;
    int v = (t < KE * NBKT) ? bucketTotal[t] : 0;
    sd[t] = v;
    __syncthreads();
    for (int off = 1; off < 1024; off <<= 1) {
        int u = (t >= off) ? sd[t - off] : 0;
        __syncthreads();
        sd[t] += u;
        __syncthreads();
    }
    if (t < KE * NBKT) bucketStart[t] = sd[t] - v;
}

__global__ void bucket_scatter_kernel(const int* __restrict__ src, const int* __restrict__ dst,
                                      const int* __restrict__ bucketStart,
                                      const int* __restrict__ blockBase,
                                      uint2* __restrict__ ebuf) {
    const int blk = blockIdx.x;
    const int k = blk / NEB, cb = blk - k * NEB;
    __shared__ int hist[NBKT], binoff[NBKT], cur[NBKT];
    __shared__ int sc[256];
    __shared__ uint2 stage[EPB];
    const int t = threadIdx.x;
    for (int i = t; i < NBKT; i += 256) hist[i] = 0;
    __syncthreads();
    const int e0 = cb * EPB, e1 = min(e0 + EPB, NE);
    for (int e = e0 + t; e < e1; e += 256)
        atomicAdd(&hist[dst[(size_t)k * NE + e] >> 9], 1);
    __syncthreads();
    int hv = (t < NBKT) ? hist[t] : 0;
    sc[t] = hv;
    __syncthreads();
    for (int off = 1; off < 256; off <<= 1) {
        int u = (t >= off) ? sc[t - off] : 0;
        __syncthreads();
        sc[t] += u;
        __syncthreads();
    }
    if (t < NBKT) { binoff[t] = sc[t] - hv; cur[t] = sc[t] - hv; }
    __syncthreads();
    for (int e = e0 + t; e < e1; e += 256) {
        int d = dst[(size_t)k * NE + e], s = src[(size_t)k * NE + e];
        int b = d >> 9;
        int p = atomicAdd(&cur[b], 1);
        stage[p] = make_uint2((unsigned)s, (unsigned)d);
    }
    __syncthreads();
    const int n = e1 - e0;
    for (int i = t; i < n; i += 256) {
        uint2 ed = stage[i];
        int b = (int)(ed.y >> 9);
        int pos = bucketStart[k * NBKT + b] + blockBase[(size_t)blk * NBKT + b] + (i - binoff[b]);
        ebuf[pos] = ed;
    }
}

__global__ void bucket_deg_kernel(const uint2* __restrict__ ebuf,
                                  const int* __restrict__ bucketStart, int* __restrict__ degi) {
    const int blk = blockIdx.x;               // KE*NBKT
    const int k = blk / NBKT, b = blk - k * NBKT;
    __shared__ int cnt[512];
    for (int i = threadIdx.x; i < 512; i += 256) cnt[i] = 0;
    __syncthreads();
    const int s0 = bucketStart[blk];
    const int s1 = (blk + 1 < KE * NBKT) ? bucketStart[blk + 1] : KE * NE;
    for (int e = s0 + threadIdx.x; e < s1; e += 256)
        atomicAdd(&cnt[ebuf[e].y & 511], 1);
    __syncthreads();
    const int n0 = b << 9;
    for (int i = threadIdx.x; i < 512; i += 256) {
        int node = n0 + i;
        if (node < NN) degi[(size_t)k * NN + node] = cnt[i];
    }
}

__global__ void scan_a_kernel(const int* __restrict__ degi, int* __restrict__ bsum) {
    const int b = blockIdx.x;
    const int k = b / NB, lb = b - k * NB;
    const int t = threadIdx.x;
    const int i = lb * 256 + t;
    int deg = (i < NN) ? degi[(size_t)k * NN + i] : 0;
    __shared__ int sd[256];
    sd[t] = deg;
    __syncthreads();
    for (int off = 128; off > 0; off >>= 1) {
        if (t < off) sd[t] += sd[t + off];
        __syncthreads();
    }
    if (t == 0) bsum[b] = sd[0];
}

__global__ void scan_b_kernel(int* __restrict__ bsum) {
    const int k = blockIdx.x;
    const int t = threadIdx.x;          // 512
    int v = (t < NB) ? bsum[k * NB + t] : 0;
    __shared__ int sd[512];
    sd[t] = v;
    __syncthreads();
    for (int off = 1; off < 512; off <<= 1) {
        int u = (t >= off) ? sd[t - off] : 0;
        __syncthreads();
        sd[t] += u;
        __syncthreads();
    }
    if (t < NB) bsum[k * NB + t] = sd[t] - v;
}

__global__ void scan_c_kernel(const int* __restrict__ degi, const int* __restrict__ bsum,
                              int* __restrict__ rowptr, float* __restrict__ invdeg) {
    const int b = blockIdx.x;
    const int k = b / NB, lb = b - k * NB;
    const int t = threadIdx.x;
    const int i = lb * 256 + t;
    int deg = (i < NN) ? degi[(size_t)k * NN + i] : 0;
    __shared__ int sd[256];
    sd[t] = deg;
    __syncthreads();
    for (int off = 1; off < 256; off <<= 1) {
        int u = (t >= off) ? sd[t - off] : 0;
        __syncthreads();
        sd[t] += u;
        __syncthreads();
    }
    int val = bsum[b] + sd[t] - deg;
    if (i < NN) {
        rowptr[(size_t)k * (NN + 1) + i] = val;
        invdeg[(size_t)k * NN + i] = 1.0f / (float)max(deg, 1);
    }
    if (i == NN) rowptr[(size_t)k * (NN + 1) + NN] = NE;
}

__global__ void bucket_fill_kernel(const uint2* __restrict__ ebuf,
                                   const int* __restrict__ bucketStart,
                                   const int* __restrict__ rowptr, int* __restrict__ csr) {
    const int blk = blockIdx.x;
    const int k = blk / NBKT, b = blk - k * NBKT;
    __shared__ int cur[512];
    const int n0 = b << 9;
    for (int i = threadIdx.x; i < 512; i += 256) {
        int node = n0 + i;
        cur[i] = (node < NN) ? rowptr[(size_t)k * (NN + 1) + node] : 0;
    }
    __syncthreads();
    const int s0 = bucketStart[blk];
    const int s1 = (blk + 1 < KE * NBKT) ? bucketStart[blk + 1] : KE * NE;
    for (int e = s0 + threadIdx.x; e < s1; e += 256) {
        uint2 ed = ebuf[e];
        int p = atomicAdd(&cur[ed.y & 511], 1);
        csr[(size_t)k * NE + p] = (int)ed.x;
    }
}

// ---- gather (all 3 etypes), bf16 rows, 16 lanes/node, 4 edges in flight ----
// affine!=0: apply BN of previous layer post-aggregation:
//   neigh_post = sc * mean(acc_src) + (deg>0 ? sh : 0)
__global__ void gather3_kernel(const ushort* __restrict__ hsrc, const int* __restrict__ csr,
                               const int* __restrict__ rowptr, const float* __restrict__ invdeg,
                               ushort* __restrict__ neigh, const float* __restrict__ ssl,
                               int affine) {
    int g = blockIdx.x * 16 + (threadIdx.x >> 4);
    if (g >= KE * NN) return;
    int k = g / NN, node = g - k * NN;
    const int q = (threadIdx.x & 15) * 8;
    const int* rp = rowptr + (size_t)k * (NN + 1) + node;
    const int* cs = csr + (size_t)k * NE;
    int beg = rp[0], end = rp[1];
    float f0=0,f1=0,f2=0,f3=0,f4=0,f5=0,f6=0,f7=0;
    int j = beg;
    for (; j + 4 <= end; j += 4) {
        int s0 = cs[j], s1 = cs[j + 1], s2 = cs[j + 2], s3 = cs[j + 3];
        uint4 a = *(const uint4*)(hsrc + (size_t)s0 * D + q);
        uint4 b = *(const uint4*)(hsrc + (size_t)s1 * D + q);
        uint4 c = *(const uint4*)(hsrc + (size_t)s2 * D + q);
        uint4 d = *(const uint4*)(hsrc + (size_t)s3 * D + q);
        f0 += bf2f(a.x & 0xffff) + bf2f(b.x & 0xffff) + bf2f(c.x & 0xffff) + bf2f(d.x & 0xffff);
        f1 += bf2f(a.x >> 16)    + bf2f(b.x >> 16)    + bf2f(c.x >> 16)    + bf2f(d.x >> 16);
        f2 += bf2f(a.y & 0xffff) + bf2f(b.y & 0xffff) + bf2f(c.y & 0xffff) + bf2f(d.y & 0xffff);
        f3 += bf2f(a.y >> 16)    + bf2f(b.y >> 16)    + bf2f(c.y >> 16)    + bf2f(d.y >> 16);
        f4 += bf2f(a.z & 0xffff) + bf2f(b.z & 0xffff) + bf2f(c.z & 0xffff) + bf2f(d.z & 0xffff);
        f5 += bf2f(a.z >> 16)    + bf2f(b.z >> 16)    + bf2f(c.z >> 16)    + bf2f(d.z >> 16);
        f6 += bf2f(a.w & 0xffff) + bf2f(b.w & 0xffff) + bf2f(c.w & 0xffff) + bf2f(d.w & 0xffff);
        f7 += bf2f(a.w >> 16)    + bf2f(b.w >> 16)    + bf2f(c.w >> 16)    + bf2f(d.w >> 16);
    }
    for (; j < end; ++j) {
        int s0 = cs[j];
        uint4 a = *(const uint4*)(hsrc + (size_t)s0 * D + q);
        f0 += bf2f(a.x & 0xffff); f1 += bf2f(a.x >> 16);
        f2 += bf2f(a.y & 0xffff); f3 += bf2f(a.y >> 16);
        f4 += bf2f(a.z & 0xffff); f5 += bf2f(a.z >> 16);
        f6 += bf2f(a.w & 0xffff); f7 += bf2f(a.w >> 16);
    }
    float iv = invdeg[g];
    float r0 = f0 * iv, r1 = f1 * iv, r2 = f2 * iv, r3 = f3 * iv;
    float r4 = f4 * iv, r5 = f5 * iv, r6 = f6 * iv, r7 = f7 * iv;
    if (affine) {
        float4 c0 = *(const float4*)(ssl + q);
        float4 c1 = *(const float4*)(ssl + q + 4);
        float4 h0 = *(const float4*)(ssl + D + q);
        float4 h1 = *(const float4*)(ssl + D + q + 4);
        float m = (end > beg) ? 1.0f : 0.0f;   // deg==0 -> neighbor feat is exactly 0
        r0 = r0 * c0.x + m * h0.x;  r1 = r1 * c0.y + m * h0.y;
        r2 = r2 * c0.z + m * h0.z;  r3 = r3 * c0.w + m * h0.w;
        r4 = r4 * c1.x + m * h1.x;  r5 = r5 * c1.y + m * h1.y;
        r6 = r6 * c1.z + m * h1.z;  r7 = r7 * c1.w + m * h1.w;
    }
    uint4 o;
    o.x = pack2(r0, r1);
    o.y = pack2(r2, r3);
    o.z = pack2(r4, r5);
    o.w = pack2(r6, r7);
    *(uint4*)(neigh + (size_t)k * NNP * D + (size_t)node * D + q) = o;
}

// ---- fused layer GEMM + column stats; persistent self-A tile in LDS ----
// LDS swizzle (both-sides, rule #21): within each [128][64]-ushort subtile,
// stored col-chunk c (16B) of row r holds global chunk c ^ (r&7); readers XOR the same.
__global__ __launch_bounds__(256, 2)
void layer_gemm_kernel(const ushort* __restrict__ hself, const ushort* __restrict__ neigh,
                       const ushort* __restrict__ Bt,
                       const float* __restrict__ bias,
                       ushort* __restrict__ accb, int relu,
                       float* __restrict__ colsum, float* __restrict__ colsq) {
    __shared__ __align__(16) ushort Asf[2][128][64];   // 32 KB self-A (persistent)
    __shared__ __align__(16) ushort Anb[2][128][64];   // 32 KB neigh-A (per etype)
    __shared__ __align__(16) ushort Bst[128][64];      // 16 KB B chunk (per part/kc)
    const int tid  = threadIdx.x;
    const int wave = tid >> 6, lane = tid & 63;
    const int wm = wave & 1, wn = wave >> 1;
    const int lrow = lane & 15, quad = lane >> 4;
    const int m0 = blockIdx.x * 128;
    // staging geometry (gload16): lane -> row = w*32+i*8+(lane>>3), col chunk = lane&7
    const int srow  = lane >> 3;
    const int scolb = ((lane & 7) ^ srow) << 4;        // pre-swizzled source col byte

    // ---- stage self A tile once (reused for all 3 etypes) ----
    {
        const char* Ab = (const char*)hself + (size_t)m0 * 256;
        #pragma unroll
        for (int kc = 0; kc < 2; ++kc)
            #pragma unroll
            for (int i = 0; i < 4; ++i)
                gload16(Ab + (size_t)(wave * 32 + i * 8 + srow) * 256 + kc * 128 + scolb,
                        (char*)Asf + kc * 16384 + wave * 4096 + i * 1024);
    }

    floatx4 tot[4][4];
    #pragma unroll
    for (int a = 0; a < 4; ++a)
        #pragma unroll
        for (int b = 0; b < 4; ++b)
            tot[a][b] = (floatx4){0.f, 0.f, 0.f, 0.f};

    for (int k = 0; k < KE; ++k) {
        const char* Btk = (const char*)Bt + (size_t)k * 65536;   // 128 n-rows * 512 B
        __syncthreads();                       // prior Anb/Bst reads complete
        // stage neigh A (both kc) + first B chunk (self, kc0)
        {
            const char* Ab = (const char*)(neigh + (size_t)k * NNP * D) + (size_t)m0 * 256;
            #pragma unroll
            for (int kc = 0; kc < 2; ++kc)
                #pragma unroll
                for (int i = 0; i < 4; ++i)
                    gload16(Ab + (size_t)(wave * 32 + i * 8 + srow) * 256 + kc * 128 + scolb,
                            (char*)Anb + kc * 16384 + wave * 4096 + i * 1024);
        }
        #pragma unroll
        for (int i = 0; i < 4; ++i)
            gload16(Btk + (size_t)(wave * 32 + i * 8 + srow) * 512 + scolb,
                    (char*)Bst + wave * 4096 + i * 1024);

        floatx4 o4[4][4];
        #pragma unroll
        for (int a = 0; a < 4; ++a)
            #pragma unroll
            for (int b = 0; b < 4; ++b)
                o4[a][b] = (floatx4){0.f, 0.f, 0.f, 0.f};
        // idx: 0=self/kc0, 1=self/kc1, 2=neigh/kc0, 3=neigh/kc1
        #pragma unroll
        for (int idx = 0; idx < 4; ++idx) {
            __syncthreads();                   // staged data visible
            const char* Ab = (idx >> 1) ? (const char*)Anb : (const char*)Asf;
            const int kcoff = (idx & 1) * 16384;
            #pragma unroll
            for (int ks = 0; ks < 2; ++ks) {
                short8 af[4], bfr[4];
                const int cb = ks * 64 + quad * 16;
                #pragma unroll
                for (int im = 0; im < 4; ++im) {
                    int ra = wm * 64 + im * 16 + lrow;
                    af[im] = *(const short8*)(Ab + kcoff + ra * 128 + (cb ^ ((ra & 7) << 4)));
                }
                #pragma unroll
                for (int in = 0; in < 4; ++in) {
                    int rb = wn * 64 + in * 16 + lrow;
                    bfr[in] = *(const short8*)((const char*)Bst + rb * 128 + (cb ^ ((rb & 7) << 4)));
                }
                #pragma unroll
                for (int im = 0; im < 4; ++im)
                    #pragma unroll
                    for (int in = 0; in < 4; ++in)
                        o4[im][in] = __builtin_amdgcn_mfma_f32_16x16x32_bf16(
                            af[im], bfr[in], o4[im][in], 0, 0, 0);
            }
            if (idx < 3) {
                __syncthreads();               // Bst reads done -> restage
                const int p2 = (idx + 1) >> 1, k2 = (idx + 1) & 1;
                #pragma unroll
                for (int i = 0; i < 4; ++i)
                    gload16(Btk + (size_t)(wave * 32 + i * 8 + srow) * 512 + p2 * 256 + k2 * 128 + scolb,
                            (char*)Bst + wave * 4096 + i * 1024);
            }
        }
        const float* bk = bias + k * D;
        float bv[4];
        #pragma unroll
        for (int in = 0; in < 4; ++in) bv[in] = bk[wn * 64 + in * 16 + lrow];
        #pragma unroll
        for (int im = 0; im < 4; ++im)
            #pragma unroll
            for (int in = 0; in < 4; ++in)
                #pragma unroll
                for (int r = 0; r < 4; ++r) {
                    float v = o4[im][in][r] + bv[in];
                    if (relu) v = fmaxf(v, 0.f);
                    tot[im][in][r] += v;
                }
    }

    // ---- fused column stats from fp32 registers (mask tail rows >= NN) ----
    float ls[4] = {0.f, 0.f, 0.f, 0.f}, lq[4] = {0.f, 0.f, 0.f, 0.f};
    #pragma unroll
    for (int im = 0; im < 4; ++im)
        #pragma unroll
        for (int r = 0; r < 4; ++r) {
            int row = m0 + wm * 64 + im * 16 + quad * 4 + r;
            bool ok = row < NN;
            #pragma unroll
            for (int in = 0; in < 4; ++in) {
                float v = ok ? tot[im][in][r] : 0.f;
                ls[in] += v;
                lq[in] += v * v;
            }
        }
    __syncthreads();                                   // all MFMA LDS reads done
    float* redS = (float*)&Anb[0][0][0];               // [128][8] floats (in Anb)
    float* redQ = redS + 1024;
    #pragma unroll
    for (int in = 0; in < 4; ++in) {
        int col = wn * 64 + in * 16 + lrow;
        int slot = col * 8 + wm * 4 + quad;
        redS[slot] = ls[in];
        redQ[slot] = lq[in];
    }
    __syncthreads();
    if (tid < 128) {
        float s = 0.f, q = 0.f;
        #pragma unroll
        for (int i = 0; i < 8; ++i) { s += redS[tid * 8 + i]; q += redQ[tid * 8 + i]; }
        int slice = blockIdx.x & (NSL - 1);
        atomic_add_f32(&colsum[slice * D + tid], s);
        atomic_add_f32(&colsq[slice * D + tid], q);
    }

    // ---- C tile -> LDS (bf16, Asf region; disjoint from redS/redQ in Anb) ----
    ushort* Cs = &Asf[0][0][0];                        // [128][128] ushort = 32 KB
    #pragma unroll
    for (int im = 0; im < 4; ++im)
        #pragma unroll
        for (int r = 0; r < 4; ++r) {
            int rl = wm * 64 + im * 16 + quad * 4 + r;
            #pragma unroll
            for (int in = 0; in < 4; ++in)
                Cs[rl * 128 + wn * 64 + in * 16 + lrow] = (ushort)f2bf(tot[im][in][r]);
        }
    __syncthreads();
    #pragma unroll
    for (int jj = 0; jj < 8; ++jj) {
        int c8 = tid + jj * 256;           // uint4 index
        int rl = c8 >> 4;                  // 16 uint4 per 128-col row
        int cc = (c8 & 15) * 8;
        int row = m0 + rl;
        if (row < NN)
            *(uint4*)(accb + (size_t)row * D + cc) = *(const uint4*)(Cs + rl * 128 + cc);
    }
}

// ---- batchnorm finalize (also re-zeros stats for the next layer) ----
__global__ void finalize_kernel(float* __restrict__ colsum, float* __restrict__ colsq,
                                const float* __restrict__ gamma, const float* __restrict__ beta,
                                float* __restrict__ ssl) {
    int c = threadIdx.x;  // 128
    float s = 0.f, q = 0.f;
    #pragma unroll
    for (int i = 0; i < NSL; ++i) { s += colsum[i * D + c]; q += colsq[i * D + c]; }
    float mu  = s * (1.0f / NN);
    float var = q * (1.0f / NN) - mu * mu;
    float sc  = gamma[c] * rsqrtf(var + EPS);
    ssl[c]     = sc;
    ssl[D + c] = beta[c] - mu * sc;
    #pragma unroll
    for (int i = 0; i < NSL; ++i) { colsum[i * D + c] = 0.f; colsq[i * D + c] = 0.f; }
}

// ---- final BN apply (fp32 out), only for the last layer ----
__global__ void bn_kernel(const ushort* __restrict__ accb, const float* __restrict__ ssl,
                          float* __restrict__ out) {
    size_t i = (size_t)blockIdx.x * blockDim.x + threadIdx.x;
    if (i >= (size_t)NN * D / 4) return;
    int c4 = (int)(i & 31) << 2;
    uint2 a = *(const uint2*)(accb + i * 4);
    float4 v = {bf2f(a.x & 0xffff), bf2f(a.x >> 16), bf2f(a.y & 0xffff), bf2f(a.y >> 16)};
    float4 sc = *(const float4*)(ssl + c4);
    float4 sh = *(const float4*)(ssl + D + c4);
    float4 o;
    o.x = v.x * sc.x + sh.x;
    o.y = v.y * sc.y + sh.y;
    o.z = v.z * sc.z + sh.z;
    o.w = v.w * sc.w + sh.w;
    *(float4*)(out + i * 4) = o;
}

extern "C" void kernel_launch(void* const* d_in, const int* in_sizes, int n_in,
                              void* d_out, int out_size, void* d_ws, size_t ws_size,
                              hipStream_t stream) {
    const float* x       = (const float*)d_in[0];
    const int*   src     = (const int*)d_in[1];
    const int*   dst     = (const int*)d_in[2];
    const float* W_self  = (const float*)d_in[3];
    const float* W_neigh = (const float*)d_in[4];
    const float* bvec    = (const float*)d_in[5];
    const float* gamma   = (const float*)d_in[6];
    const float* beta    = (const float*)d_in[7];
    float* out = (float*)d_out;

    // ---- workspace layout ----
    ushort* accb   = (ushort*)d_ws;                       // NNP*D bf16 (pre-BN activations)
    float*  invdeg = (float*)(accb + (size_t)NNP * D);    // KE*NN
    float*  colsum = invdeg + (size_t)KE * NN;            // NSL*D
    float*  colsq  = colsum + NSL * D;                    // NSL*D
    float*  ss     = colsq + NSL * D;                     // NL*2*D (per-layer BN affine)
    float*  biasW  = ss + NL * 2 * D;                     // KE*D (folded bias)
    ushort* hbf    = (ushort*)(biasW + KE * D);           // NNP*D bf16 (x only)
    ushort* neigh  = hbf + (size_t)NNP * D;               // KE*NNP*D bf16
    ushort* Btw    = neigh + (size_t)KE * NNP * D;        // NL*KE*128*256 bf16
    int*    degi   = (int*)(Btw + (size_t)NL * KE * 128 * 256);  // KE*NN
    int*    rowptr = degi + (size_t)KE * NN;              // KE*(NN+1)
    int*    csr    = rowptr + (size_t)KE * (NN + 1);      // KE*NE
    int*    bsum   = csr + (size_t)KE * NE;               // KE*NB
    int*    bucketTotal = bsum + (size_t)KE * NB;         // KE*NBKT
    int*    bucketStart = bucketTotal + KE * NBKT;        // KE*NBKT
    int*    blockBase   = bucketStart + KE * NBKT;        // KE*NEB*NBKT
    uint2*  ebuf   = (uint2*)accb;  // aliases accb (14.4MB <= 25.6MB); CSR build precedes layer loop

    convert_x_kernel<<<(int)(((size_t)NN * D / 4 + 255) / 256), 256, 0, stream>>>(x, hbf);
    wprep_kernel<<<(NL * KE * 128 * 256 + 255) / 256, 256, 0, stream>>>(W_self, W_neigh, Btw);
    hipMemsetAsync(colsum, 0, sizeof(float) * 2 * NSL * D, stream);

    hipMemsetAsync(bucketTotal, 0, sizeof(int) * KE * NBKT, stream);
    bucket_count_kernel<<<KE * NEB, 256, 0, stream>>>(dst, bucketTotal, blockBase);
    bucket_scan_kernel<<<1, 1024, 0, stream>>>(bucketTotal, bucketStart);
    bucket_scatter_kernel<<<KE * NEB, 256, 0, stream>>>(src, dst, bucketStart, blockBase, ebuf);
    bucket_deg_kernel<<<KE * NBKT, 256, 0, stream>>>(ebuf, bucketStart, degi);
    scan_a_kernel<<<KE * NB, 256, 0, stream>>>(degi, bsum);
    scan_b_kernel<<<KE, 512, 0, stream>>>(bsum);
    scan_c_kernel<<<KE * NB, 256, 0, stream>>>(degi, bsum, rowptr, invdeg);
    bucket_fill_kernel<<<KE * NBKT, 256, 0, stream>>>(ebuf, bucketStart, rowptr, csr);

    for (int l = 0; l < NL; ++l) {
        int relu = (l < NL - 1) ? 1 : 0;
        const ushort* hsrc = (l == 0) ? hbf : accb;      // accb = pre-BN acts of layer l-1
        const float*  ssl  = ss + (size_t)(l ? l - 1 : 0) * 2 * D;
        gather3_kernel<<<(KE * NN + 15) / 16, 256, 0, stream>>>(
            hsrc, csr, rowptr, invdeg, neigh, ssl, l > 0);
        layer_gemm_kernel<<<NNP / 128, 256, 0, stream>>>(
            hsrc, neigh,
            Btw + (size_t)l * KE * 128 * 256,
            (l == 0) ? bvec : biasW,
            accb, relu, colsum, colsq);
        finalize_kernel<<<1, 128, 0, stream>>>(colsum, colsq, gamma + (size_t)l * D,
                                               beta + (size_t)l * D, ss + (size_t)l * 2 * D);
        if (l + 1 < NL)
            fold_kernel<<<KE, 128, 0, stream>>>(
                W_self + (size_t)(l + 1) * KE * D * D,
                bvec + (size_t)(l + 1) * KE * D,
                ss + (size_t)l * 2 * D,
                Btw + (size_t)(l + 1) * KE * 128 * 256,
                biasW);
    }
    bn_kernel<<<(int)(((size_t)NN * D / 4 + 255) / 256), 256, 0, stream>>>(
        accb, ss + (size_t)(NL - 1) * 2 * D, out);
}

// Round 6
// 572.100 us; speedup vs baseline: 1.4938x; 1.0265x over previous
//
#include <hip/hip_runtime.h>

#define NN 100000
#define NNP 100096   // NN padded to multiple of 128 (GEMM tail reads)
#define NE 600000
#define KE 3
#define NL 3
#define D  128
#define EPS 1e-5f
#define NB 391       // ceil(NN/256) blocks per etype for the scan
#define NBKT 196     // buckets per etype: dst>>9 (512 nodes/bucket)
#define EPB 4096     // edges per block in bucket passes
#define NEB 147      // ceil(NE/EPB)
#define NSL 16       // stat slices (atomic contention spread)

typedef __attribute__((ext_vector_type(8))) short short8;
typedef __attribute__((ext_vector_type(4))) float floatx4;

__device__ __forceinline__ void atomic_add_f32(float* p, float v) { unsafeAtomicAdd(p, v); }

__device__ __forceinline__ float bf2f(unsigned int u16) {
    unsigned int v = u16 << 16;
    return __builtin_bit_cast(float, v);
}
__device__ __forceinline__ unsigned int f2bf(float f) {   // RNE
    unsigned int u = __builtin_bit_cast(unsigned int, f);
    u += 0x7FFFu + ((u >> 16) & 1u);
    return u >> 16;
}
__device__ __forceinline__ unsigned int pack2(float a, float b) {
    return f2bf(a) | (f2bf(b) << 16);
}

// async global->LDS, 16B per lane; LDS dest = wave-uniform base + lane*16
__device__ __forceinline__ void gload16(const void* g, void* l) {
    __builtin_amdgcn_global_load_lds(
        (const __attribute__((address_space(1))) void*)g,
        (__attribute__((address_space(3))) void*)l, 16, 0, 0);
}

// ---- x (fp32) -> h (bf16) ----
__global__ void convert_x_kernel(const float* __restrict__ x, ushort* __restrict__ hbf) {
    size_t i = (size_t)blockIdx.x * blockDim.x + threadIdx.x;
    if (i >= (size_t)NN * D / 4) return;
    float4 v = *(const float4*)(x + i * 4);
    uint2 o;
    o.x = pack2(v.x, v.y);
    o.y = pack2(v.z, v.w);
    *(uint2*)(hbf + i * 4) = o;
}

// ---- W prep: Bt[l,k][n][kk] bf16 ----
__global__ void wprep_kernel(const float* __restrict__ Ws, const float* __restrict__ Wn,
                             ushort* __restrict__ Bt) {
    int idx = blockIdx.x * blockDim.x + threadIdx.x;
    if (idx >= NL * KE * 128 * 256) return;
    int lk  = idx >> 15;
    int rem = idx & 32767;
    int n   = rem >> 8;
    int kk  = rem & 255;
    float v = (kk < 128) ? Ws[(size_t)lk * 16384 + kk * 128 + n]
                         : Wn[(size_t)lk * 16384 + (kk - 128) * 128 + n];
    Bt[idx] = (ushort)f2bf(v);
}

// ---- BN fold for layer l>=1: Bt_self' = diag(sc)*Ws, bias' = b + sh@Ws ----
__global__ void fold_kernel(const float* __restrict__ Wsl, const float* __restrict__ bsrc,
                            const float* __restrict__ ssl, ushort* __restrict__ Btl,
                            float* __restrict__ biasW) {
    const int k = blockIdx.x;      // KE
    const int n = threadIdx.x;     // 128
    const float* W = Wsl + (size_t)k * D * D;
    ushort* B = Btl + (size_t)k * 32768;
    float acc = 0.f;
    #pragma unroll 4
    for (int kk = 0; kk < D; ++kk) {
        float w = W[kk * D + n];
        acc += ssl[D + kk] * w;
        B[n * 256 + kk] = (ushort)f2bf(ssl[kk] * w);
    }
    biasW[k * D + n] = bsrc[k * D + n] + acc;
}

// ==== CSR build: two-level bucket sort ====
__global__ void bucket_count_kernel(const int* __restrict__ dst,
                                    int* __restrict__ bucketTotal, int* __restrict__ blockBase) {
    const int blk = blockIdx.x;               // KE*NEB
    const int k = blk / NEB, cb = blk - k * NEB;
    __shared__ int hist[NBKT];
    for (int i = threadIdx.x; i < NBKT; i += 256) hist[i] = 0;
    __syncthreads();
    const int e0 = cb * EPB, e1 = min(e0 + EPB, NE);
    for (int e = e0 + threadIdx.x; e < e1; e += 256)
        atomicAdd(&hist[dst[(size_t)k * NE + e] >> 9], 1);
    __syncthreads();
    for (int i = threadIdx.x; i < NBKT; i += 256) {
        int c = hist[i];
        int base = c ? atomicAdd(&bucketTotal[k * NBKT + i], c) : 0;
        blockBase[(size_t)blk * NBKT + i] = base;
    }
}

__global__ void bucket_scan_kernel(const int* __restrict__ bucketTotal,
                                   int* __restrict__ bucketStart) {
    __shared__ int sd[1024];
    const int t = threadIdx.x;
    int v = (t < KE * NBKT) ? bucketTotal[t] : 0;
    sd[t] = v;
    __syncthreads();
    for (int off = 1; off < 1024; off <<= 1) {
        int u = (t >= off) ? sd[t - off] : 0;
        __syncthreads();
        sd[t] += u;
        __syncthreads();
    }
    if (t < KE * NBKT) bucketStart[t] = sd[t] - v;
}

__global__ void bucket_scatter_kernel(const int* __restrict__ src, const int* __restrict__ dst,
                                      const int* __restrict__ bucketStart,
                                      const int* __restrict__ blockBase,
                                      uint2* __restrict__ ebuf) {
    const int blk = blockIdx.x;
    const int k = blk / NEB, cb = blk - k * NEB;
    __shared__ int hist[NBKT], binoff[NBKT], cur[NBKT];
    __shared__ int sc[256];
    __shared__ uint2 stage[EPB];
    const int t = threadIdx.x;
    for (int i = t; i < NBKT; i += 256) hist[i] = 0;
    __syncthreads();
    const int e0 = cb * EPB, e1 = min(e0 + EPB, NE);
    for (int e = e0 + t; e < e1; e += 256)
        atomicAdd(&hist[dst[(size_t)k * NE + e] >> 9], 1);
    __syncthreads();
    int hv = (t < NBKT) ? hist[t] : 0;
    sc[t] = hv;
    __syncthreads();
    for (int off = 1; off < 256; off <<= 1) {
        int u = (t >= off) ? sc[t - off] : 0;
        __syncthreads();
        sc[t] += u;
        __syncthreads();
    }
    if (t < NBKT) { binoff[t] = sc[t] - hv; cur[t] = sc[t] - hv; }
    __syncthreads();
    for (int e = e0 + t; e < e1; e += 256) {
        int d = dst[(size_t)k * NE + e], s = src[(size_t)k * NE + e];
        int b = d >> 9;
        int p = atomicAdd(&cur[b], 1);
        stage[p] = make_uint2((unsigned)s, (unsigned)d);
    }
    __syncthreads();
    const int n = e1 - e0;
    for (int i = t; i < n; i += 256) {
        uint2 ed = stage[i];
        int b = (int)(ed.y >> 9);
        int pos = bucketStart[k * NBKT + b] + blockBase[(size_t)blk * NBKT + b] + (i - binoff[b]);
        ebuf[pos] = ed;
    }
}

__global__ void bucket_deg_kernel(const uint2* __restrict__ ebuf,
                                  const int* __restrict__ bucketStart, int* __restrict__ degi) {
    const int blk = blockIdx.x;               // KE*NBKT
    const int k = blk / NBKT, b = blk - k * NBKT;
    __shared__ int cnt[512];
    for (int i = threadIdx.x; i < 512; i += 256) cnt[i] = 0;
    __syncthreads();
    const int s0 = bucketStart[blk];
    const int s1 = (blk + 1 < KE * NBKT) ? bucketStart[blk + 1] : KE * NE;
    for (int e = s0 + threadIdx.x; e < s1; e += 256)
        atomicAdd(&cnt[ebuf[e].y & 511], 1);
    __syncthreads();
    const int n0 = b << 9;
    for (int i = threadIdx.x; i < 512; i += 256) {
        int node = n0 + i;
        if (node < NN) degi[(size_t)k * NN + node] = cnt[i];
    }
}

__global__ void scan_a_kernel(const int* __restrict__ degi, int* __restrict__ bsum) {
    const int b = blockIdx.x;
    const int k = b / NB, lb = b - k * NB;
    const int t = threadIdx.x;
    const int i = lb * 256 + t;
    int deg = (i < NN) ? degi[(size_t)k * NN + i] : 0;
    __shared__ int sd[256];
    sd[t] = deg;
    __syncthreads();
    for (int off = 128; off > 0; off >>= 1) {
        if (t < off) sd[t] += sd[t + off];
        __syncthreads();
    }
    if (t == 0) bsum[b] = sd[0];
}

__global__ void scan_b_kernel(int* __restrict__ bsum) {
    const int k = blockIdx.x;
    const int t = threadIdx.x;          // 512
    int v = (t < NB) ? bsum[k * NB + t] : 0;
    __shared__ int sd[512];
    sd[t] = v;
    __syncthreads();
    for (int off = 1; off < 512; off <<= 1) {
        int u = (t >= off) ? sd[t - off] : 0;
        __syncthreads();
        sd[t] += u;
        __syncthreads();
    }
    if (t < NB) bsum[k * NB + t] = sd[t] - v;
}

__global__ void scan_c_kernel(const int* __restrict__ degi, const int* __restrict__ bsum,
                              int* __restrict__ rowptr, float* __restrict__ invdeg) {
    const int b = blockIdx.x;
    const int k = b / NB, lb = b - k * NB;
    const int t = threadIdx.x;
    const int i = lb * 256 + t;
    int deg = (i < NN) ? degi[(size_t)k * NN + i] : 0;
    __shared__ int sd[256];
    sd[t] = deg;
    __syncthreads();
    for (int off = 1; off < 256; off <<= 1) {
        int u = (t >= off) ? sd[t - off] : 0;
        __syncthreads();
        sd[t] += u;
        __syncthreads();
    }
    int val = bsum[b] + sd[t] - deg;
    if (i < NN) {
        rowptr[(size_t)k * (NN + 1) + i] = val;
        invdeg[(size_t)k * NN + i] = 1.0f / (float)max(deg, 1);
    }
    if (i == NN) rowptr[(size_t)k * (NN + 1) + NN] = NE;
}

__global__ void bucket_fill_kernel(const uint2* __restrict__ ebuf,
                                   const int* __restrict__ bucketStart,
                                   const int* __restrict__ rowptr, int* __restrict__ csr) {
    const int blk = blockIdx.x;
    const int k = blk / NBKT, b = blk - k * NBKT;
    __shared__ int cur[512];
    const int n0 = b << 9;
    for (int i = threadIdx.x; i < 512; i += 256) {
        int node = n0 + i;
        cur[i] = (node < NN) ? rowptr[(size_t)k * (NN + 1) + node] : 0;
    }
    __syncthreads();
    const int s0 = bucketStart[blk];
    const int s1 = (blk + 1 < KE * NBKT) ? bucketStart[blk + 1] : KE * NE;
    for (int e = s0 + threadIdx.x; e < s1; e += 256) {
        uint2 ed = ebuf[e];
        int p = atomicAdd(&cur[ed.y & 511], 1);
        csr[(size_t)k * NE + p] = (int)ed.x;
    }
}

// ---- gather (all 3 etypes), bf16 rows, 16 lanes/node, 4 edges in flight ----
// affine!=0: apply BN of previous layer post-aggregation:
//   neigh_post = sc * mean(acc_src) + (deg>0 ? sh : 0)
__global__ void gather3_kernel(const ushort* __restrict__ hsrc, const int* __restrict__ csr,
                               const int* __restrict__ rowptr, const float* __restrict__ invdeg,
                               ushort* __restrict__ neigh, const float* __restrict__ ssl,
                               int affine) {
    int g = blockIdx.x * 16 + (threadIdx.x >> 4);
    if (g >= KE * NN) return;
    int k = g / NN, node = g - k * NN;
    const int q = (threadIdx.x & 15) * 8;
    const int* rp = rowptr + (size_t)k * (NN + 1) + node;
    const int* cs = csr + (size_t)k * NE;
    int beg = rp[0], end = rp[1];
    float f0=0,f1=0,f2=0,f3=0,f4=0,f5=0,f6=0,f7=0;
    int j = beg;
    for (; j + 4 <= end; j += 4) {
        int s0 = cs[j], s1 = cs[j + 1], s2 = cs[j + 2], s3 = cs[j + 3];
        uint4 a = *(const uint4*)(hsrc + (size_t)s0 * D + q);
        uint4 b = *(const uint4*)(hsrc + (size_t)s1 * D + q);
        uint4 c = *(const uint4*)(hsrc + (size_t)s2 * D + q);
        uint4 d = *(const uint4*)(hsrc + (size_t)s3 * D + q);
        f0 += bf2f(a.x & 0xffff) + bf2f(b.x & 0xffff) + bf2f(c.x & 0xffff) + bf2f(d.x & 0xffff);
        f1 += bf2f(a.x >> 16)    + bf2f(b.x >> 16)    + bf2f(c.x >> 16)    + bf2f(d.x >> 16);
        f2 += bf2f(a.y & 0xffff) + bf2f(b.y & 0xffff) + bf2f(c.y & 0xffff) + bf2f(d.y & 0xffff);
        f3 += bf2f(a.y >> 16)    + bf2f(b.y >> 16)    + bf2f(c.y >> 16)    + bf2f(d.y >> 16);
        f4 += bf2f(a.z & 0xffff) + bf2f(b.z & 0xffff) + bf2f(c.z & 0xffff) + bf2f(d.z & 0xffff);
        f5 += bf2f(a.z >> 16)    + bf2f(b.z >> 16)    + bf2f(c.z >> 16)    + bf2f(d.z >> 16);
        f6 += bf2f(a.w & 0xffff) + bf2f(b.w & 0xffff) + bf2f(c.w & 0xffff) + bf2f(d.w & 0xffff);
        f7 += bf2f(a.w >> 16)    + bf2f(b.w >> 16)    + bf2f(c.w >> 16)    + bf2f(d.w >> 16);
    }
    for (; j < end; ++j) {
        int s0 = cs[j];
        uint4 a = *(const uint4*)(hsrc + (size_t)s0 * D + q);
        f0 += bf2f(a.x & 0xffff); f1 += bf2f(a.x >> 16);
        f2 += bf2f(a.y & 0xffff); f3 += bf2f(a.y >> 16);
        f4 += bf2f(a.z & 0xffff); f5 += bf2f(a.z >> 16);
        f6 += bf2f(a.w & 0xffff); f7 += bf2f(a.w >> 16);
    }
    float iv = invdeg[g];
    float r0 = f0 * iv, r1 = f1 * iv, r2 = f2 * iv, r3 = f3 * iv;
    float r4 = f4 * iv, r5 = f5 * iv, r6 = f6 * iv, r7 = f7 * iv;
    if (affine) {
        float4 c0 = *(const float4*)(ssl + q);
        float4 c1 = *(const float4*)(ssl + q + 4);
        float4 h0 = *(const float4*)(ssl + D + q);
        float4 h1 = *(const float4*)(ssl + D + q + 4);
        float m = (end > beg) ? 1.0f : 0.0f;   // deg==0 -> neighbor feat is exactly 0
        r0 = r0 * c0.x + m * h0.x;  r1 = r1 * c0.y + m * h0.y;
        r2 = r2 * c0.z + m * h0.z;  r3 = r3 * c0.w + m * h0.w;
        r4 = r4 * c1.x + m * h1.x;  r5 = r5 * c1.y + m * h1.y;
        r6 = r6 * c1.z + m * h1.z;  r7 = r7 * c1.w + m * h1.w;
    }
    uint4 o;
    o.x = pack2(r0, r1);
    o.y = pack2(r2, r3);
    o.z = pack2(r4, r5);
    o.w = pack2(r6, r7);
    *(uint4*)(neigh + (size_t)k * NNP * D + (size_t)node * D + q) = o;
}

// ---- fused layer GEMM + column stats; 512 threads, 8 waves (2Mx4N), 128-row tile ----
// Per-wave output 64x32 -> o4[4][2]+tot[4][2] = 64 acc regs -> ~115 VGPR -> 16 waves/CU.
// LDS swizzle (both-sides, rule #21): within each [128][64]-ushort subtile,
// stored col-chunk c (16B) of row r holds global chunk c ^ (r&7); readers XOR the same.
__global__ __launch_bounds__(512, 4)
void layer_gemm_kernel(const ushort* __restrict__ hself, const ushort* __restrict__ neigh,
                       const ushort* __restrict__ Bt,
                       const float* __restrict__ bias,
                       ushort* __restrict__ accb, int relu,
                       float* __restrict__ colsum, float* __restrict__ colsq) {
    __shared__ __align__(16) ushort Asf[2][128][64];   // 32 KB self-A (persistent)
    __shared__ __align__(16) ushort Anb[2][128][64];   // 32 KB neigh-A (per etype)
    __shared__ __align__(16) ushort Bst[128][64];      // 16 KB B chunk (per part/kc)
    const int tid  = threadIdx.x;
    const int wave = tid >> 6, lane = tid & 63;        // 8 waves
    const int wm = wave & 1, wn = wave >> 1;           // wm 0..1 (rows), wn 0..3 (cols)
    const int lrow = lane & 15, quad = lane >> 4;
    const int m0 = blockIdx.x * 128;
    // staging geometry (gload16): lane -> row = base + (lane>>3), col chunk = lane&7
    const int srow  = lane >> 3;
    const int scolb = ((lane & 7) ^ srow) << 4;        // pre-swizzled source col byte

    // ---- stage self A tile once (reused for all 3 etypes): 2 gload16/wave/kc ----
    {
        const char* Ab = (const char*)hself + (size_t)m0 * 256;
        #pragma unroll
        for (int kc = 0; kc < 2; ++kc)
            #pragma unroll
            for (int i = 0; i < 2; ++i)
                gload16(Ab + (size_t)(wave * 16 + i * 8 + srow) * 256 + kc * 128 + scolb,
                        (char*)Asf + kc * 16384 + wave * 2048 + i * 1024);
    }

    floatx4 tot[4][2];
    #pragma unroll
    for (int a = 0; a < 4; ++a)
        #pragma unroll
        for (int b = 0; b < 2; ++b)
            tot[a][b] = (floatx4){0.f, 0.f, 0.f, 0.f};

    for (int k = 0; k < KE; ++k) {
        const char* Btk = (const char*)Bt + (size_t)k * 65536;   // 128 n-rows * 512 B
        __syncthreads();                       // prior Anb/Bst reads complete
        // stage neigh A (both kc) + first B chunk (self, kc0)
        {
            const char* Ab = (const char*)(neigh + (size_t)k * NNP * D) + (size_t)m0 * 256;
            #pragma unroll
            for (int kc = 0; kc < 2; ++kc)
                #pragma unroll
                for (int i = 0; i < 2; ++i)
                    gload16(Ab + (size_t)(wave * 16 + i * 8 + srow) * 256 + kc * 128 + scolb,
                            (char*)Anb + kc * 16384 + wave * 2048 + i * 1024);
        }
        #pragma unroll
        for (int i = 0; i < 2; ++i)
            gload16(Btk + (size_t)(wave * 16 + i * 8 + srow) * 512 + scolb,
                    (char*)Bst + wave * 2048 + i * 1024);

        floatx4 o4[4][2];
        #pragma unroll
        for (int a = 0; a < 4; ++a)
            #pragma unroll
            for (int b = 0; b < 2; ++b)
                o4[a][b] = (floatx4){0.f, 0.f, 0.f, 0.f};
        // idx: 0=self/kc0, 1=self/kc1, 2=neigh/kc0, 3=neigh/kc1
        #pragma unroll
        for (int idx = 0; idx < 4; ++idx) {
            __syncthreads();                   // staged data visible
            const char* Ab = (idx >> 1) ? (const char*)Anb : (const char*)Asf;
            const int kcoff = (idx & 1) * 16384;
            #pragma unroll
            for (int ks = 0; ks < 2; ++ks) {
                short8 af[4], bfr[2];
                const int cb = ks * 64 + quad * 16;
                #pragma unroll
                for (int im = 0; im < 4; ++im) {
                    int ra = wm * 64 + im * 16 + lrow;
                    af[im] = *(const short8*)(Ab + kcoff + ra * 128 + (cb ^ ((ra & 7) << 4)));
                }
                #pragma unroll
                for (int in = 0; in < 2; ++in) {
                    int rb = wn * 32 + in * 16 + lrow;
                    bfr[in] = *(const short8*)((const char*)Bst + rb * 128 + (cb ^ ((rb & 7) << 4)));
                }
                #pragma unroll
                for (int im = 0; im < 4; ++im)
                    #pragma unroll
                    for (int in = 0; in < 2; ++in)
                        o4[im][in] = __builtin_amdgcn_mfma_f32_16x16x32_bf16(
                            af[im], bfr[in], o4[im][in], 0, 0, 0);
            }
            if (idx < 3) {
                __syncthreads();               // Bst reads done -> restage
                const int p2 = (idx + 1) >> 1, k2 = (idx + 1) & 1;
                #pragma unroll
                for (int i = 0; i < 2; ++i)
                    gload16(Btk + (size_t)(wave * 16 + i * 8 + srow) * 512 + p2 * 256 + k2 * 128 + scolb,
                            (char*)Bst + wave * 2048 + i * 1024);
            }
        }
        const float* bk = bias + k * D;
        float bv[2];
        #pragma unroll
        for (int in = 0; in < 2; ++in) bv[in] = bk[wn * 32 + in * 16 + lrow];
        #pragma unroll
        for (int im = 0; im < 4; ++im)
            #pragma unroll
            for (int in = 0; in < 2; ++in)
                #pragma unroll
                for (int r = 0; r < 4; ++r) {
                    float v = o4[im][in][r] + bv[in];
                    if (relu) v = fmaxf(v, 0.f);
                    tot[im][in][r] += v;
                }
    }

    // ---- fused column stats from fp32 registers (mask tail rows >= NN) ----
    float ls[2] = {0.f, 0.f}, lq[2] = {0.f, 0.f};
    #pragma unroll
    for (int im = 0; im < 4; ++im)
        #pragma unroll
        for (int r = 0; r < 4; ++r) {
            int row = m0 + wm * 64 + im * 16 + quad * 4 + r;
            bool ok = row < NN;
            #pragma unroll
            for (int in = 0; in < 2; ++in) {
                float v = ok ? tot[im][in][r] : 0.f;
                ls[in] += v;
                lq[in] += v * v;
            }
        }
    __syncthreads();                                   // all MFMA LDS reads done
    float* redS = (float*)&Anb[0][0][0];               // [128][8] floats (in Anb)
    float* redQ = redS + 1024;
    #pragma unroll
    for (int in = 0; in < 2; ++in) {
        int col = wn * 32 + in * 16 + lrow;
        int slot = col * 8 + wm * 4 + quad;            // (wm,quad) unique per col
        redS[slot] = ls[in];
        redQ[slot] = lq[in];
    }
    __syncthreads();
    if (tid < 128) {
        float s = 0.f, q = 0.f;
        #pragma unroll
        for (int i = 0; i < 8; ++i) { s += redS[tid * 8 + i]; q += redQ[tid * 8 + i]; }
        int slice = blockIdx.x & (NSL - 1);
        atomic_add_f32(&colsum[slice * D + tid], s);
        atomic_add_f32(&colsq[slice * D + tid], q);
    }

    // ---- C tile -> LDS (bf16, Asf region; disjoint from redS/redQ in Anb) ----
    ushort* Cs = &Asf[0][0][0];                        // [128][128] ushort = 32 KB
    #pragma unroll
    for (int im = 0; im < 4; ++im)
        #pragma unroll
        for (int r = 0; r < 4; ++r) {
            int rl = wm * 64 + im * 16 + quad * 4 + r;
            #pragma unroll
            for (int in = 0; in < 2; ++in)
                Cs[rl * 128 + wn * 32 + in * 16 + lrow] = (ushort)f2bf(tot[im][in][r]);
        }
    __syncthreads();
    #pragma unroll
    for (int jj = 0; jj < 4; ++jj) {
        int c8 = tid + jj * 512;           // uint4 index, 2048 total
        int rl = c8 >> 4;                  // 16 uint4 per 128-col row
        int cc = (c8 & 15) * 8;
        int row = m0 + rl;
        if (row < NN)
            *(uint4*)(accb + (size_t)row * D + cc) = *(const uint4*)(Cs + rl * 128 + cc);
    }
}

// ---- batchnorm finalize (per-layer stat slices; zeroed once upfront) ----
__global__ void finalize_kernel(const float* __restrict__ colsum, const float* __restrict__ colsq,
                                const float* __restrict__ gamma, const float* __restrict__ beta,
                                float* __restrict__ ssl) {
    int c = threadIdx.x;  // 128
    float s = 0.f, q = 0.f;
    #pragma unroll
    for (int i = 0; i < NSL; ++i) { s += colsum[i * D + c]; q += colsq[i * D + c]; }
    float mu  = s * (1.0f / NN);
    float var = q * (1.0f / NN) - mu * mu;
    float sc  = gamma[c] * rsqrtf(var + EPS);
    ssl[c]     = sc;
    ssl[D + c] = beta[c] - mu * sc;
}

// ---- final BN apply (fp32 out), only for the last layer ----
__global__ void bn_kernel(const ushort* __restrict__ accb, const float* __restrict__ ssl,
                          float* __restrict__ out) {
    size_t i = (size_t)blockIdx.x * blockDim.x + threadIdx.x;
    if (i >= (size_t)NN * D / 4) return;
    int c4 = (int)(i & 31) << 2;
    uint2 a = *(const uint2*)(accb + i * 4);
    float4 v = {bf2f(a.x & 0xffff), bf2f(a.x >> 16), bf2f(a.y & 0xffff), bf2f(a.y >> 16)};
    float4 sc = *(const float4*)(ssl + c4);
    float4 sh = *(const float4*)(ssl + D + c4);
    float4 o;
    o.x = v.x * sc.x + sh.x;
    o.y = v.y * sc.y + sh.y;
    o.z = v.z * sc.z + sh.z;
    o.w = v.w * sc.w + sh.w;
    *(float4*)(out + i * 4) = o;
}

extern "C" void kernel_launch(void* const* d_in, const int* in_sizes, int n_in,
                              void* d_out, int out_size, void* d_ws, size_t ws_size,
                              hipStream_t stream) {
    const float* x       = (const float*)d_in[0];
    const int*   src     = (const int*)d_in[1];
    const int*   dst     = (const int*)d_in[2];
    const float* W_self  = (const float*)d_in[3];
    const float* W_neigh = (const float*)d_in[4];
    const float* bvec    = (const float*)d_in[5];
    const float* gamma   = (const float*)d_in[6];
    const float* beta    = (const float*)d_in[7];
    float* out = (float*)d_out;

    // ---- workspace layout ----
    ushort* accb   = (ushort*)d_ws;                       // NNP*D bf16 (pre-BN activations)
    float*  invdeg = (float*)(accb + (size_t)NNP * D);    // KE*NN
    float*  colsum = invdeg + (size_t)KE * NN;            // NL*NSL*D (per-layer slices)
    float*  colsq  = colsum + NL * NSL * D;               // NL*NSL*D
    float*  ss     = colsq + NL * NSL * D;                // NL*2*D (per-layer BN affine)
    float*  biasW  = ss + NL * 2 * D;                     // KE*D (folded bias)
    ushort* hbf    = (ushort*)(biasW + KE * D);           // NNP*D bf16 (x only)
    ushort* neigh  = hbf + (size_t)NNP * D;               // KE*NNP*D bf16
    ushort* Btw    = neigh + (size_t)KE * NNP * D;        // NL*KE*128*256 bf16
    int*    degi   = (int*)(Btw + (size_t)NL * KE * 128 * 256);  // KE*NN
    int*    rowptr = degi + (size_t)KE * NN;              // KE*(NN+1)
    int*    csr    = rowptr + (size_t)KE * (NN + 1);      // KE*NE
    int*    bsum   = csr + (size_t)KE * NE;               // KE*NB
    int*    bucketTotal = bsum + (size_t)KE * NB;         // KE*NBKT
    int*    bucketStart = bucketTotal + KE * NBKT;        // KE*NBKT
    int*    blockBase   = bucketStart + KE * NBKT;        // KE*NEB*NBKT
    uint2*  ebuf   = (uint2*)accb;  // aliases accb (14.4MB <= 25.6MB); CSR build precedes layer loop

    convert_x_kernel<<<(int)(((size_t)NN * D / 4 + 255) / 256), 256, 0, stream>>>(x, hbf);
    wprep_kernel<<<(NL * KE * 128 * 256 + 255) / 256, 256, 0, stream>>>(W_self, W_neigh, Btw);
    hipMemsetAsync(colsum, 0, sizeof(float) * 2 * NL * NSL * D, stream);

    hipMemsetAsync(bucketTotal, 0, sizeof(int) * KE * NBKT, stream);
    bucket_count_kernel<<<KE * NEB, 256, 0, stream>>>(dst, bucketTotal, blockBase);
    bucket_scan_kernel<<<1, 1024, 0, stream>>>(bucketTotal, bucketStart);
    bucket_scatter_kernel<<<KE * NEB, 256, 0, stream>>>(src, dst, bucketStart, blockBase, ebuf);
    bucket_deg_kernel<<<KE * NBKT, 256, 0, stream>>>(ebuf, bucketStart, degi);
    scan_a_kernel<<<KE * NB, 256, 0, stream>>>(degi, bsum);
    scan_b_kernel<<<KE, 512, 0, stream>>>(bsum);
    scan_c_kernel<<<KE * NB, 256, 0, stream>>>(degi, bsum, rowptr, invdeg);
    bucket_fill_kernel<<<KE * NBKT, 256, 0, stream>>>(ebuf, bucketStart, rowptr, csr);

    for (int l = 0; l < NL; ++l) {
        int relu = (l < NL - 1) ? 1 : 0;
        const ushort* hsrc = (l == 0) ? hbf : accb;      // accb = pre-BN acts of layer l-1
        const float*  ssl  = ss + (size_t)(l ? l - 1 : 0) * 2 * D;
        gather3_kernel<<<(KE * NN + 15) / 16, 256, 0, stream>>>(
            hsrc, csr, rowptr, invdeg, neigh, ssl, l > 0);
        layer_gemm_kernel<<<NNP / 128, 512, 0, stream>>>(
            hsrc, neigh,
            Btw + (size_t)l * KE * 128 * 256,
            (l == 0) ? bvec : biasW,
            accb, relu,
            colsum + (size_t)l * NSL * D, colsq + (size_t)l * NSL * D);
        finalize_kernel<<<1, 128, 0, stream>>>(
            colsum + (size_t)l * NSL * D, colsq + (size_t)l * NSL * D,
            gamma + (size_t)l * D, beta + (size_t)l * D, ss + (size_t)l * 2 * D);
        if (l + 1 < NL)
            fold_kernel<<<KE, 128, 0, stream>>>(
                W_self + (size_t)(l + 1) * KE * D * D,
                bvec + (size_t)(l + 1) * KE * D,
                ss + (size_t)l * 2 * D,
                Btw + (size_t)(l + 1) * KE * 128 * 256,
                biasW);
    }
    bn_kernel<<<(int)(((size_t)NN * D / 4 + 255) / 256), 256, 0, stream>>>(
        accb, ss + (size_t)(NL - 1) * 2 * D, out);
}

// Round 7
// 553.883 us; speedup vs baseline: 1.5429x; 1.0329x over previous
//
#include <hip/hip_runtime.h>

#define NN 100000
#define NNP 100096   // NN padded to multiple of 128 (GEMM tail reads)
#define NE 600000
#define KE 3
#define NL 3
#define D  128
#define EPS 1e-5f
#define NB 391       // ceil(NN/256) blocks per etype for the scan
#define NBKT 196     // buckets per etype: dst>>9 (512 nodes/bucket)
#define EPB 4096     // edges per block in bucket passes
#define NEB 147      // ceil(NE/EPB)
#define NSL 16       // stat slices (atomic contention spread)

typedef __attribute__((ext_vector_type(8))) short short8;
typedef __attribute__((ext_vector_type(4))) float floatx4;

__device__ __forceinline__ void atomic_add_f32(float* p, float v) { unsafeAtomicAdd(p, v); }

__device__ __forceinline__ float bf2f(unsigned int u16) {
    unsigned int v = u16 << 16;
    return __builtin_bit_cast(float, v);
}
__device__ __forceinline__ unsigned int f2bf(float f) {   // RNE
    unsigned int u = __builtin_bit_cast(unsigned int, f);
    u += 0x7FFFu + ((u >> 16) & 1u);
    return u >> 16;
}
__device__ __forceinline__ unsigned int pack2(float a, float b) {
    return f2bf(a) | (f2bf(b) << 16);
}

// async global->LDS, 16B per lane; LDS dest = wave-uniform base + lane*16
__device__ __forceinline__ void gload16(const void* g, void* l) {
    __builtin_amdgcn_global_load_lds(
        (const __attribute__((address_space(1))) void*)g,
        (__attribute__((address_space(3))) void*)l, 16, 0, 0);
}

// ---- x (fp32) -> h (bf16) ----
__global__ void convert_x_kernel(const float* __restrict__ x, ushort* __restrict__ hbf) {
    size_t i = (size_t)blockIdx.x * blockDim.x + threadIdx.x;
    if (i >= (size_t)NN * D / 4) return;
    float4 v = *(const float4*)(x + i * 4);
    uint2 o;
    o.x = pack2(v.x, v.y);
    o.y = pack2(v.z, v.w);
    *(uint2*)(hbf + i * 4) = o;
}

// ---- W prep: Bt[l,k][n][kk] bf16 ----
__global__ void wprep_kernel(const float* __restrict__ Ws, const float* __restrict__ Wn,
                             ushort* __restrict__ Bt) {
    int idx = blockIdx.x * blockDim.x + threadIdx.x;
    if (idx >= NL * KE * 128 * 256) return;
    int lk  = idx >> 15;
    int rem = idx & 32767;
    int n   = rem >> 8;
    int kk  = rem & 255;
    float v = (kk < 128) ? Ws[(size_t)lk * 16384 + kk * 128 + n]
                         : Wn[(size_t)lk * 16384 + (kk - 128) * 128 + n];
    Bt[idx] = (ushort)f2bf(v);
}

// ---- BN fold for layer l>=1: Bt_self' = diag(sc)*Ws, bias' = b + sh@Ws ----
__global__ void fold_kernel(const float* __restrict__ Wsl, const float* __restrict__ bsrc,
                            const float* __restrict__ ssl, ushort* __restrict__ Btl,
                            float* __restrict__ biasW) {
    const int k = blockIdx.x;      // KE
    const int n = threadIdx.x;     // 128
    const float* W = Wsl + (size_t)k * D * D;
    ushort* B = Btl + (size_t)k * 32768;
    float acc = 0.f;
    #pragma unroll 4
    for (int kk = 0; kk < D; ++kk) {
        float w = W[kk * D + n];
        acc += ssl[D + kk] * w;
        B[n * 256 + kk] = (ushort)f2bf(ssl[kk] * w);
    }
    biasW[k * D + n] = bsrc[k * D + n] + acc;
}

// ==== CSR build: two-level bucket sort ====
__global__ void bucket_count_kernel(const int* __restrict__ dst,
                                    int* __restrict__ bucketTotal, int* __restrict__ blockBase) {
    const int blk = blockIdx.x;               // KE*NEB
    const int k = blk / NEB, cb = blk - k * NEB;
    __shared__ int hist[NBKT];
    for (int i = threadIdx.x; i < NBKT; i += 256) hist[i] = 0;
    __syncthreads();
    const int e0 = cb * EPB, e1 = min(e0 + EPB, NE);
    for (int e = e0 + threadIdx.x; e < e1; e += 256)
        atomicAdd(&hist[dst[(size_t)k * NE + e] >> 9], 1);
    __syncthreads();
    for (int i = threadIdx.x; i < NBKT; i += 256) {
        int c = hist[i];
        int base = c ? atomicAdd(&bucketTotal[k * NBKT + i], c) : 0;
        blockBase[(size_t)blk * NBKT + i] = base;
    }
}

__global__ void bucket_scan_kernel(const int* __restrict__ bucketTotal,
                                   int* __restrict__ bucketStart) {
    __shared__ int sd[1024];
    const int t = threadIdx.x;
    int v = (t < KE * NBKT) ? bucketTotal[t] : 0;
    sd[t] = v;
    __syncthreads();
    for (int off = 1; off < 1024; off <<= 1) {
        int u = (t >= off) ? sd[t - off] : 0;
        __syncthreads();
        sd[t] += u;
        __syncthreads();
    }
    if (t < KE * NBKT) bucketStart[t] = sd[t] - v;
}

__global__ void bucket_scatter_kernel(const int* __restrict__ src, const int* __restrict__ dst,
                                      const int* __restrict__ bucketStart,
                                      const int* __restrict__ blockBase,
                                      uint2* __restrict__ ebuf) {
    const int blk = blockIdx.x;
    const int k = blk / NEB, cb = blk - k * NEB;
    __shared__ int hist[NBKT], binoff[NBKT], cur[NBKT];
    __shared__ int sc[256];
    __shared__ uint2 stage[EPB];
    const int t = threadIdx.x;
    for (int i = t; i < NBKT; i += 256) hist[i] = 0;
    __syncthreads();
    const int e0 = cb * EPB, e1 = min(e0 + EPB, NE);
    for (int e = e0 + t; e < e1; e += 256)
        atomicAdd(&hist[dst[(size_t)k * NE + e] >> 9], 1);
    __syncthreads();
    int hv = (t < NBKT) ? hist[t] : 0;
    sc[t] = hv;
    __syncthreads();
    for (int off = 1; off < 256; off <<= 1) {
        int u = (t >= off) ? sc[t - off] : 0;
        __syncthreads();
        sc[t] += u;
        __syncthreads();
    }
    if (t < NBKT) { binoff[t] = sc[t] - hv; cur[t] = sc[t] - hv; }
    __syncthreads();
    for (int e = e0 + t; e < e1; e += 256) {
        int d = dst[(size_t)k * NE + e], s = src[(size_t)k * NE + e];
        int b = d >> 9;
        int p = atomicAdd(&cur[b], 1);
        stage[p] = make_uint2((unsigned)s, (unsigned)d);
    }
    __syncthreads();
    const int n = e1 - e0;
    for (int i = t; i < n; i += 256) {
        uint2 ed = stage[i];
        int b = (int)(ed.y >> 9);
        int pos = bucketStart[k * NBKT + b] + blockBase[(size_t)blk * NBKT + b] + (i - binoff[b]);
        ebuf[pos] = ed;
    }
}

__global__ void bucket_deg_kernel(const uint2* __restrict__ ebuf,
                                  const int* __restrict__ bucketStart, int* __restrict__ degi) {
    const int blk = blockIdx.x;               // KE*NBKT
    const int k = blk / NBKT, b = blk - k * NBKT;
    __shared__ int cnt[512];
    for (int i = threadIdx.x; i < 512; i += 256) cnt[i] = 0;
    __syncthreads();
    const int s0 = bucketStart[blk];
    const int s1 = (blk + 1 < KE * NBKT) ? bucketStart[blk + 1] : KE * NE;
    for (int e = s0 + threadIdx.x; e < s1; e += 256)
        atomicAdd(&cnt[ebuf[e].y & 511], 1);
    __syncthreads();
    const int n0 = b << 9;
    for (int i = threadIdx.x; i < 512; i += 256) {
        int node = n0 + i;
        if (node < NN) degi[(size_t)k * NN + node] = cnt[i];
    }
}

__global__ void scan_a_kernel(const int* __restrict__ degi, int* __restrict__ bsum) {
    const int b = blockIdx.x;
    const int k = b / NB, lb = b - k * NB;
    const int t = threadIdx.x;
    const int i = lb * 256 + t;
    int deg = (i < NN) ? degi[(size_t)k * NN + i] : 0;
    __shared__ int sd[256];
    sd[t] = deg;
    __syncthreads();
    for (int off = 128; off > 0; off >>= 1) {
        if (t < off) sd[t] += sd[t + off];
        __syncthreads();
    }
    if (t == 0) bsum[b] = sd[0];
}

__global__ void scan_b_kernel(int* __restrict__ bsum) {
    const int k = blockIdx.x;
    const int t = threadIdx.x;          // 512
    int v = (t < NB) ? bsum[k * NB + t] : 0;
    __shared__ int sd[512];
    sd[t] = v;
    __syncthreads();
    for (int off = 1; off < 512; off <<= 1) {
        int u = (t >= off) ? sd[t - off] : 0;
        __syncthreads();
        sd[t] += u;
        __syncthreads();
    }
    if (t < NB) bsum[k * NB + t] = sd[t] - v;
}

__global__ void scan_c_kernel(const int* __restrict__ degi, const int* __restrict__ bsum,
                              int* __restrict__ rowptr, float* __restrict__ invdeg) {
    const int b = blockIdx.x;
    const int k = b / NB, lb = b - k * NB;
    const int t = threadIdx.x;
    const int i = lb * 256 + t;
    int deg = (i < NN) ? degi[(size_t)k * NN + i] : 0;
    __shared__ int sd[256];
    sd[t] = deg;
    __syncthreads();
    for (int off = 1; off < 256; off <<= 1) {
        int u = (t >= off) ? sd[t - off] : 0;
        __syncthreads();
        sd[t] += u;
        __syncthreads();
    }
    int val = bsum[b] + sd[t] - deg;
    if (i < NN) {
        rowptr[(size_t)k * (NN + 1) + i] = val;
        invdeg[(size_t)k * NN + i] = 1.0f / (float)max(deg, 1);
    }
    if (i == NN) rowptr[(size_t)k * (NN + 1) + NN] = NE;
}

__global__ void bucket_fill_kernel(const uint2* __restrict__ ebuf,
                                   const int* __restrict__ bucketStart,
                                   const int* __restrict__ rowptr, int* __restrict__ csr) {
    const int blk = blockIdx.x;
    const int k = blk / NBKT, b = blk - k * NBKT;
    __shared__ int cur[512];
    const int n0 = b << 9;
    for (int i = threadIdx.x; i < 512; i += 256) {
        int node = n0 + i;
        cur[i] = (node < NN) ? rowptr[(size_t)k * (NN + 1) + node] : 0;
    }
    __syncthreads();
    const int s0 = bucketStart[blk];
    const int s1 = (blk + 1 < KE * NBKT) ? bucketStart[blk + 1] : KE * NE;
    for (int e = s0 + threadIdx.x; e < s1; e += 256) {
        uint2 ed = ebuf[e];
        int p = atomicAdd(&cur[ed.y & 511], 1);
        csr[(size_t)k * NE + p] = (int)ed.x;
    }
}

// ---- gather (all 3 etypes), bf16 rows, 16 lanes/node, 4 edges in flight ----
// affine!=0: apply BN of previous layer post-aggregation:
//   neigh_post = sc * mean(acc_src) + (deg>0 ? sh : 0)
__global__ void gather3_kernel(const ushort* __restrict__ hsrc, const int* __restrict__ csr,
                               const int* __restrict__ rowptr, const float* __restrict__ invdeg,
                               ushort* __restrict__ neigh, const float* __restrict__ ssl,
                               int affine) {
    int g = blockIdx.x * 16 + (threadIdx.x >> 4);
    if (g >= KE * NN) return;
    int k = g / NN, node = g - k * NN;
    const int q = (threadIdx.x & 15) * 8;
    const int* rp = rowptr + (size_t)k * (NN + 1) + node;
    const int* cs = csr + (size_t)k * NE;
    int beg = rp[0], end = rp[1];
    float f0=0,f1=0,f2=0,f3=0,f4=0,f5=0,f6=0,f7=0;
    int j = beg;
    for (; j + 4 <= end; j += 4) {
        int s0 = cs[j], s1 = cs[j + 1], s2 = cs[j + 2], s3 = cs[j + 3];
        uint4 a = *(const uint4*)(hsrc + (size_t)s0 * D + q);
        uint4 b = *(const uint4*)(hsrc + (size_t)s1 * D + q);
        uint4 c = *(const uint4*)(hsrc + (size_t)s2 * D + q);
        uint4 d = *(const uint4*)(hsrc + (size_t)s3 * D + q);
        f0 += bf2f(a.x & 0xffff) + bf2f(b.x & 0xffff) + bf2f(c.x & 0xffff) + bf2f(d.x & 0xffff);
        f1 += bf2f(a.x >> 16)    + bf2f(b.x >> 16)    + bf2f(c.x >> 16)    + bf2f(d.x >> 16);
        f2 += bf2f(a.y & 0xffff) + bf2f(b.y & 0xffff) + bf2f(c.y & 0xffff) + bf2f(d.y & 0xffff);
        f3 += bf2f(a.y >> 16)    + bf2f(b.y >> 16)    + bf2f(c.y >> 16)    + bf2f(d.y >> 16);
        f4 += bf2f(a.z & 0xffff) + bf2f(b.z & 0xffff) + bf2f(c.z & 0xffff) + bf2f(d.z & 0xffff);
        f5 += bf2f(a.z >> 16)    + bf2f(b.z >> 16)    + bf2f(c.z >> 16)    + bf2f(d.z >> 16);
        f6 += bf2f(a.w & 0xffff) + bf2f(b.w & 0xffff) + bf2f(c.w & 0xffff) + bf2f(d.w & 0xffff);
        f7 += bf2f(a.w >> 16)    + bf2f(b.w >> 16)    + bf2f(c.w >> 16)    + bf2f(d.w >> 16);
    }
    for (; j < end; ++j) {
        int s0 = cs[j];
        uint4 a = *(const uint4*)(hsrc + (size_t)s0 * D + q);
        f0 += bf2f(a.x & 0xffff); f1 += bf2f(a.x >> 16);
        f2 += bf2f(a.y & 0xffff); f3 += bf2f(a.y >> 16);
        f4 += bf2f(a.z & 0xffff); f5 += bf2f(a.z >> 16);
        f6 += bf2f(a.w & 0xffff); f7 += bf2f(a.w >> 16);
    }
    float iv = invdeg[g];
    float r0 = f0 * iv, r1 = f1 * iv, r2 = f2 * iv, r3 = f3 * iv;
    float r4 = f4 * iv, r5 = f5 * iv, r6 = f6 * iv, r7 = f7 * iv;
    if (affine) {
        float4 c0 = *(const float4*)(ssl + q);
        float4 c1 = *(const float4*)(ssl + q + 4);
        float4 h0 = *(const float4*)(ssl + D + q);
        float4 h1 = *(const float4*)(ssl + D + q + 4);
        float m = (end > beg) ? 1.0f : 0.0f;   // deg==0 -> neighbor feat is exactly 0
        r0 = r0 * c0.x + m * h0.x;  r1 = r1 * c0.y + m * h0.y;
        r2 = r2 * c0.z + m * h0.z;  r3 = r3 * c0.w + m * h0.w;
        r4 = r4 * c1.x + m * h1.x;  r5 = r5 * c1.y + m * h1.y;
        r6 = r6 * c1.z + m * h1.z;  r7 = r7 * c1.w + m * h1.w;
    }
    uint4 o;
    o.x = pack2(r0, r1);
    o.y = pack2(r2, r3);
    o.z = pack2(r4, r5);
    o.w = pack2(r6, r7);
    *(uint4*)(neigh + (size_t)k * NNP * D + (size_t)node * D + q) = o;
}

// ---- fused layer GEMM + column stats; double-buffered 12-phase pipeline ----
// 512 threads / 8 waves (2Mx4N), 128-row tile, per-wave output 64x32.
// LDS: ST[2 bufs][A 16K | B 16K] = 64 KB -> 2 blocks/CU = 16 waves/CU.
// Each phase: ONE barrier -> prefetch next chunk into buf^1 -> MFMA on buf.
// Phase p: etype k=p>>2, chunk c=p&3 (c0 self/kc0, c1 self/kc1, c2 neigh/kc0, c3 neigh/kc1).
// LDS swizzle (both-sides, rule #21): stored col-chunk cc (16B) of row r holds
// global chunk cc ^ (r&7); readers XOR the same.
__global__ __launch_bounds__(512, 4)
void layer_gemm_kernel(const ushort* __restrict__ hself, const ushort* __restrict__ neigh,
                       const ushort* __restrict__ Bt,
                       const float* __restrict__ bias,
                       ushort* __restrict__ accb, int relu,
                       float* __restrict__ colsum, float* __restrict__ colsq) {
    __shared__ __align__(16) ushort ST[2][2][128][64];   // [buf][A/B][row][col] = 64 KB
    const int tid  = threadIdx.x;
    const int wave = tid >> 6, lane = tid & 63;        // 8 waves
    const int wm = wave & 1, wn = wave >> 1;           // wm 0..1 (rows), wn 0..3 (cols)
    const int lrow = lane & 15, quad = lane >> 4;
    const int m0 = blockIdx.x * 128;
    // staging geometry (gload16): lane -> row = base + (lane>>3), col chunk = lane&7
    const int srow  = lane >> 3;
    const int scolb = ((lane & 7) ^ srow) << 4;        // pre-swizzled source col byte

#define STAGE(b, kk, cc)                                                                 \
    {                                                                                    \
        const char* Asrc = ((cc) < 2) ? (const char*)hself                               \
                                      : (const char*)(neigh + (size_t)(kk) * NNP * D);   \
        const char* Bsrc = (const char*)Bt + (size_t)(kk) * 65536;                       \
        char* Adst = (char*)&ST[b][0][0][0];                                             \
        char* Bdst = (char*)&ST[b][1][0][0];                                             \
        _Pragma("unroll")                                                                \
        for (int i = 0; i < 2; ++i) {                                                    \
            int r = wave * 16 + i * 8 + srow;                                            \
            gload16(Asrc + (size_t)(m0 + r) * 256 + ((cc) & 1) * 128 + scolb,            \
                    Adst + wave * 2048 + i * 1024);                                      \
        }                                                                                \
        _Pragma("unroll")                                                                \
        for (int i = 0; i < 2; ++i) {                                                    \
            int n = wave * 16 + i * 8 + srow;                                            \
            gload16(Bsrc + (size_t)n * 512 + (cc) * 128 + scolb,                         \
                    Bdst + wave * 2048 + i * 1024);                                      \
        }                                                                                \
    }

    floatx4 tot[4][2], o4[4][2];
    #pragma unroll
    for (int a = 0; a < 4; ++a)
        #pragma unroll
        for (int b = 0; b < 2; ++b) {
            tot[a][b] = (floatx4){0.f, 0.f, 0.f, 0.f};
            o4[a][b]  = (floatx4){0.f, 0.f, 0.f, 0.f};
        }

    // prologue: stage phase 0 (etype 0, chunk 0) into buf 0
    STAGE(0, 0, 0);

    int cur = 0;
    #pragma unroll
    for (int p = 0; p < 4 * KE; ++p) {
        __syncthreads();                       // buf[cur] staged; prior reads of buf[cur^1] done
        if (p + 1 < 4 * KE) {
            const int pn = p + 1;
            STAGE(cur ^ 1, pn >> 2, pn & 3);   // prefetch next chunk (hides under MFMA)
        }
        const char* Ab = (const char*)&ST[cur][0][0][0];
        const char* Bb = (const char*)&ST[cur][1][0][0];
        #pragma unroll
        for (int ks = 0; ks < 2; ++ks) {
            short8 af[4], bfr[2];
            const int cb = ks * 64 + quad * 16;
            #pragma unroll
            for (int im = 0; im < 4; ++im) {
                int ra = wm * 64 + im * 16 + lrow;
                af[im] = *(const short8*)(Ab + ra * 128 + (cb ^ ((ra & 7) << 4)));
            }
            #pragma unroll
            for (int in = 0; in < 2; ++in) {
                int rb = wn * 32 + in * 16 + lrow;
                bfr[in] = *(const short8*)(Bb + rb * 128 + (cb ^ ((rb & 7) << 4)));
            }
            #pragma unroll
            for (int im = 0; im < 4; ++im)
                #pragma unroll
                for (int in = 0; in < 2; ++in)
                    o4[im][in] = __builtin_amdgcn_mfma_f32_16x16x32_bf16(
                        af[im], bfr[in], o4[im][in], 0, 0, 0);
        }
        if ((p & 3) == 3) {                    // etype complete: bias + relu + accumulate
            const float* bk = bias + (p >> 2) * D;
            float bv[2];
            #pragma unroll
            for (int in = 0; in < 2; ++in) bv[in] = bk[wn * 32 + in * 16 + lrow];
            #pragma unroll
            for (int im = 0; im < 4; ++im)
                #pragma unroll
                for (int in = 0; in < 2; ++in)
                    #pragma unroll
                    for (int r = 0; r < 4; ++r) {
                        float v = o4[im][in][r] + bv[in];
                        if (relu) v = fmaxf(v, 0.f);
                        tot[im][in][r] += v;
                        o4[im][in][r] = 0.f;
                    }
        }
        cur ^= 1;
    }
#undef STAGE

    // ---- fused column stats from fp32 registers (mask tail rows >= NN) ----
    float ls[2] = {0.f, 0.f}, lq[2] = {0.f, 0.f};
    #pragma unroll
    for (int im = 0; im < 4; ++im)
        #pragma unroll
        for (int r = 0; r < 4; ++r) {
            int row = m0 + wm * 64 + im * 16 + quad * 4 + r;
            bool ok = row < NN;
            #pragma unroll
            for (int in = 0; in < 2; ++in) {
                float v = ok ? tot[im][in][r] : 0.f;
                ls[in] += v;
                lq[in] += v * v;
            }
        }
    __syncthreads();                                   // all MFMA LDS reads done
    float* redS = (float*)&ST[1][0][0][0];             // [128][8] floats (8 KB, in buf1-A)
    float* redQ = redS + 1024;
    #pragma unroll
    for (int in = 0; in < 2; ++in) {
        int col = wn * 32 + in * 16 + lrow;
        int slot = col * 8 + wm * 4 + quad;            // (wm,quad) unique per col
        redS[slot] = ls[in];
        redQ[slot] = lq[in];
    }
    __syncthreads();
    if (tid < 128) {
        float s = 0.f, q = 0.f;
        #pragma unroll
        for (int i = 0; i < 8; ++i) { s += redS[tid * 8 + i]; q += redQ[tid * 8 + i]; }
        int slice = blockIdx.x & (NSL - 1);
        atomic_add_f32(&colsum[slice * D + tid], s);
        atomic_add_f32(&colsq[slice * D + tid], q);
    }

    // ---- C tile -> LDS (bf16, buf0 region = 32 KB; disjoint from redS/redQ) ----
    ushort* Cs = &ST[0][0][0][0];                      // [128][128] ushort = 32 KB
    #pragma unroll
    for (int im = 0; im < 4; ++im)
        #pragma unroll
        for (int r = 0; r < 4; ++r) {
            int rl = wm * 64 + im * 16 + quad * 4 + r;
            #pragma unroll
            for (int in = 0; in < 2; ++in)
                Cs[rl * 128 + wn * 32 + in * 16 + lrow] = (ushort)f2bf(tot[im][in][r]);
        }
    __syncthreads();
    #pragma unroll
    for (int jj = 0; jj < 4; ++jj) {
        int c8 = tid + jj * 512;           // uint4 index, 2048 total
        int rl = c8 >> 4;                  // 16 uint4 per 128-col row
        int cc = (c8 & 15) * 8;
        int row = m0 + rl;
        if (row < NN)
            *(uint4*)(accb + (size_t)row * D + cc) = *(const uint4*)(Cs + rl * 128 + cc);
    }
}

// ---- batchnorm finalize (per-layer stat slices; zeroed once upfront) ----
__global__ void finalize_kernel(const float* __restrict__ colsum, const float* __restrict__ colsq,
                                const float* __restrict__ gamma, const float* __restrict__ beta,
                                float* __restrict__ ssl) {
    int c = threadIdx.x;  // 128
    float s = 0.f, q = 0.f;
    #pragma unroll
    for (int i = 0; i < NSL; ++i) { s += colsum[i * D + c]; q += colsq[i * D + c]; }
    float mu  = s * (1.0f / NN);
    float var = q * (1.0f / NN) - mu * mu;
    float sc  = gamma[c] * rsqrtf(var + EPS);
    ssl[c]     = sc;
    ssl[D + c] = beta[c] - mu * sc;
}

// ---- final BN apply (fp32 out), only for the last layer ----
__global__ void bn_kernel(const ushort* __restrict__ accb, const float* __restrict__ ssl,
                          float* __restrict__ out) {
    size_t i = (size_t)blockIdx.x * blockDim.x + threadIdx.x;
    if (i >= (size_t)NN * D / 4) return;
    int c4 = (int)(i & 31) << 2;
    uint2 a = *(const uint2*)(accb + i * 4);
    float4 v = {bf2f(a.x & 0xffff), bf2f(a.x >> 16), bf2f(a.y & 0xffff), bf2f(a.y >> 16)};
    float4 sc = *(const float4*)(ssl + c4);
    float4 sh = *(const float4*)(ssl + D + c4);
    float4 o;
    o.x = v.x * sc.x + sh.x;
    o.y = v.y * sc.y + sh.y;
    o.z = v.z * sc.z + sh.z;
    o.w = v.w * sc.w + sh.w;
    *(float4*)(out + i * 4) = o;
}

extern "C" void kernel_launch(void* const* d_in, const int* in_sizes, int n_in,
                              void* d_out, int out_size, void* d_ws, size_t ws_size,
                              hipStream_t stream) {
    const float* x       = (const float*)d_in[0];
    const int*   src     = (const int*)d_in[1];
    const int*   dst     = (const int*)d_in[2];
    const float* W_self  = (const float*)d_in[3];
    const float* W_neigh = (const float*)d_in[4];
    const float* bvec    = (const float*)d_in[5];
    const float* gamma   = (const float*)d_in[6];
    const float* beta    = (const float*)d_in[7];
    float* out = (float*)d_out;

    // ---- workspace layout ----
    ushort* accb   = (ushort*)d_ws;                       // NNP*D bf16 (pre-BN activations)
    float*  invdeg = (float*)(accb + (size_t)NNP * D);    // KE*NN
    float*  colsum = invdeg + (size_t)KE * NN;            // NL*NSL*D (per-layer slices)
    float*  colsq  = colsum + NL * NSL * D;               // NL*NSL*D
    float*  ss     = colsq + NL * NSL * D;                // NL*2*D (per-layer BN affine)
    float*  biasW  = ss + NL * 2 * D;                     // KE*D (folded bias)
    ushort* hbf    = (ushort*)(biasW + KE * D);           // NNP*D bf16 (x only)
    ushort* neigh  = hbf + (size_t)NNP * D;               // KE*NNP*D bf16
    ushort* Btw    = neigh + (size_t)KE * NNP * D;        // NL*KE*128*256 bf16
    int*    degi   = (int*)(Btw + (size_t)NL * KE * 128 * 256);  // KE*NN
    int*    rowptr = degi + (size_t)KE * NN;              // KE*(NN+1)
    int*    csr    = rowptr + (size_t)KE * (NN + 1);      // KE*NE
    int*    bsum   = csr + (size_t)KE * NE;               // KE*NB
    int*    bucketTotal = bsum + (size_t)KE * NB;         // KE*NBKT
    int*    bucketStart = bucketTotal + KE * NBKT;        // KE*NBKT
    int*    blockBase   = bucketStart + KE * NBKT;        // KE*NEB*NBKT
    uint2*  ebuf   = (uint2*)accb;  // aliases accb (14.4MB <= 25.6MB); CSR build precedes layer loop

    convert_x_kernel<<<(int)(((size_t)NN * D / 4 + 255) / 256), 256, 0, stream>>>(x, hbf);
    wprep_kernel<<<(NL * KE * 128 * 256 + 255) / 256, 256, 0, stream>>>(W_self, W_neigh, Btw);
    hipMemsetAsync(colsum, 0, sizeof(float) * 2 * NL * NSL * D, stream);

    hipMemsetAsync(bucketTotal, 0, sizeof(int) * KE * NBKT, stream);
    bucket_count_kernel<<<KE * NEB, 256, 0, stream>>>(dst, bucketTotal, blockBase);
    bucket_scan_kernel<<<1, 1024, 0, stream>>>(bucketTotal, bucketStart);
    bucket_scatter_kernel<<<KE * NEB, 256, 0, stream>>>(src, dst, bucketStart, blockBase, ebuf);
    bucket_deg_kernel<<<KE * NBKT, 256, 0, stream>>>(ebuf, bucketStart, degi);
    scan_a_kernel<<<KE * NB, 256, 0, stream>>>(degi, bsum);
    scan_b_kernel<<<KE, 512, 0, stream>>>(bsum);
    scan_c_kernel<<<KE * NB, 256, 0, stream>>>(degi, bsum, rowptr, invdeg);
    bucket_fill_kernel<<<KE * NBKT, 256, 0, stream>>>(ebuf, bucketStart, rowptr, csr);

    for (int l = 0; l < NL; ++l) {
        int relu = (l < NL - 1) ? 1 : 0;
        const ushort* hsrc = (l == 0) ? hbf : accb;      // accb = pre-BN acts of layer l-1
        const float*  ssl  = ss + (size_t)(l ? l - 1 : 0) * 2 * D;
        gather3_kernel<<<(KE * NN + 15) / 16, 256, 0, stream>>>(
            hsrc, csr, rowptr, invdeg, neigh, ssl, l > 0);
        layer_gemm_kernel<<<NNP / 128, 512, 0, stream>>>(
            hsrc, neigh,
            Btw + (size_t)l * KE * 128 * 256,
            (l == 0) ? bvec : biasW,
            accb, relu,
            colsum + (size_t)l * NSL * D, colsq + (size_t)l * NSL * D);
        finalize_kernel<<<1, 128, 0, stream>>>(
            colsum + (size_t)l * NSL * D, colsq + (size_t)l * NSL * D,
            gamma + (size_t)l * D, beta + (size_t)l * D, ss + (size_t)l * 2 * D);
        if (l + 1 < NL)
            fold_kernel<<<KE, 128, 0, stream>>>(
                W_self + (size_t)(l + 1) * KE * D * D,
                bvec + (size_t)(l + 1) * KE * D,
                ss + (size_t)l * 2 * D,
                Btw + (size_t)(l + 1) * KE * 128 * 256,
                biasW);
    }
    bn_kernel<<<(int)(((size_t)NN * D / 4 + 255) / 256), 256, 0, stream>>>(
        accb, ss + (size_t)(NL - 1) * 2 * D, out);
}

// Round 8
// 549.072 us; speedup vs baseline: 1.5564x; 1.0088x over previous
//
#include <hip/hip_runtime.h>

#define NN 100000
#define NNP 100096   // NN padded to multiple of 128 (GEMM tail reads)
#define NE 600000
#define KE 3
#define NL 3
#define D  128
#define EPS 1e-5f
#define NB 391       // ceil(NN/256) blocks per etype for the scan
#define NBKT 196     // buckets per etype: dst>>9 (512 nodes/bucket)
#define EPB 4096     // edges per block in bucket passes
#define NEB 147      // ceil(NE/EPB)
#define NSL 16       // stat slices (atomic contention spread)

typedef __attribute__((ext_vector_type(8))) short short8;
typedef __attribute__((ext_vector_type(4))) float floatx4;

__device__ __forceinline__ void atomic_add_f32(float* p, float v) { unsafeAtomicAdd(p, v); }

__device__ __forceinline__ float bf2f(unsigned int u16) {
    unsigned int v = u16 << 16;
    return __builtin_bit_cast(float, v);
}
__device__ __forceinline__ unsigned int f2bf(float f) {   // RNE
    unsigned int u = __builtin_bit_cast(unsigned int, f);
    u += 0x7FFFu + ((u >> 16) & 1u);
    return u >> 16;
}
__device__ __forceinline__ unsigned int pack2(float a, float b) {
    return f2bf(a) | (f2bf(b) << 16);
}

// async global->LDS, 16B per lane; LDS dest = wave-uniform base + lane*16
__device__ __forceinline__ void gload16(const void* g, void* l) {
    __builtin_amdgcn_global_load_lds(
        (const __attribute__((address_space(1))) void*)g,
        (__attribute__((address_space(3))) void*)l, 16, 0, 0);
}

// ---- x (fp32) -> h (bf16); also zeros bucketTotal (saves a memset node) ----
__global__ void convert_x_kernel(const float* __restrict__ x, ushort* __restrict__ hbf,
                                 int* __restrict__ bucketTotal) {
    size_t i = (size_t)blockIdx.x * blockDim.x + threadIdx.x;
    if (i < KE * NBKT) bucketTotal[i] = 0;
    if (i >= (size_t)NN * D / 4) return;
    float4 v = *(const float4*)(x + i * 4);
    uint2 o;
    o.x = pack2(v.x, v.y);
    o.y = pack2(v.z, v.w);
    *(uint2*)(hbf + i * 4) = o;
}

// ---- W prep: Bt[l,k][n][kk] bf16; also zeros colsum/colsq (saves a memset node) ----
__global__ void wprep_kernel(const float* __restrict__ Ws, const float* __restrict__ Wn,
                             ushort* __restrict__ Bt, float* __restrict__ colstats) {
    int idx = blockIdx.x * blockDim.x + threadIdx.x;
    if (idx >= NL * KE * 128 * 256) return;
    if (idx < 2 * NL * NSL * D) colstats[idx] = 0.f;
    int lk  = idx >> 15;
    int rem = idx & 32767;
    int n   = rem >> 8;
    int kk  = rem & 255;
    float v = (kk < 128) ? Ws[(size_t)lk * 16384 + kk * 128 + n]
                         : Wn[(size_t)lk * 16384 + (kk - 128) * 128 + n];
    Bt[idx] = (ushort)f2bf(v);
}

// ---- merged BN finalize + fold (l < NL-1): all KE blocks compute sc/sh in LDS;
// block 0 publishes ss; each block folds its etype's W_self and bias ----
__global__ void finfold_kernel(const float* __restrict__ colsum, const float* __restrict__ colsq,
                               const float* __restrict__ gamma, const float* __restrict__ beta,
                               const float* __restrict__ Wsl, const float* __restrict__ bsrc,
                               float* __restrict__ ssl, ushort* __restrict__ Btl,
                               float* __restrict__ biasW) {
    __shared__ float sc_s[D], sh_s[D];
    const int k = blockIdx.x;      // KE
    const int c = threadIdx.x;     // 128
    float s = 0.f, q = 0.f;
    #pragma unroll
    for (int i = 0; i < NSL; ++i) { s += colsum[i * D + c]; q += colsq[i * D + c]; }
    float mu  = s * (1.0f / NN);
    float var = q * (1.0f / NN) - mu * mu;
    float sc  = gamma[c] * rsqrtf(var + EPS);
    float sh  = beta[c] - mu * sc;
    sc_s[c] = sc; sh_s[c] = sh;
    if (k == 0) { ssl[c] = sc; ssl[D + c] = sh; }
    __syncthreads();
    const float* W = Wsl + (size_t)k * D * D;
    ushort* B = Btl + (size_t)k * 32768;
    float acc = 0.f;
    #pragma unroll 4
    for (int kk = 0; kk < D; ++kk) {
        float w = W[kk * D + c];
        acc += sh_s[kk] * w;
        B[c * 256 + kk] = (ushort)f2bf(sc_s[kk] * w);
    }
    biasW[k * D + c] = bsrc[k * D + c] + acc;
}

// ==== CSR build: two-level bucket sort ====
__global__ void bucket_count_kernel(const int* __restrict__ dst,
                                    int* __restrict__ bucketTotal, int* __restrict__ blockBase) {
    const int blk = blockIdx.x;               // KE*NEB
    const int k = blk / NEB, cb = blk - k * NEB;
    __shared__ int hist[NBKT];
    for (int i = threadIdx.x; i < NBKT; i += 256) hist[i] = 0;
    __syncthreads();
    const int e0 = cb * EPB, e1 = min(e0 + EPB, NE);
    for (int e = e0 + threadIdx.x; e < e1; e += 256)
        atomicAdd(&hist[dst[(size_t)k * NE + e] >> 9], 1);
    __syncthreads();
    for (int i = threadIdx.x; i < NBKT; i += 256) {
        int c = hist[i];
        int base = c ? atomicAdd(&bucketTotal[k * NBKT + i], c) : 0;
        blockBase[(size_t)blk * NBKT + i] = base;
    }
}

__global__ void bucket_scan_kernel(const int* __restrict__ bucketTotal,
                                   int* __restrict__ bucketStart) {
    __shared__ int sd[1024];
    const int t = threadIdx.x;
    int v = (t < KE * NBKT) ? bucketTotal[t] : 0;
    sd[t] = v;
    __syncthreads();
    for (int off = 1; off < 1024; off <<= 1) {
        int u = (t >= off) ? sd[t - off] : 0;
        __syncthreads();
        sd[t] += u;
        __syncthreads();
    }
    if (t < KE * NBKT) bucketStart[t] = sd[t] - v;
}

__global__ void bucket_scatter_kernel(const int* __restrict__ src, const int* __restrict__ dst,
                                      const int* __restrict__ bucketStart,
                                      const int* __restrict__ blockBase,
                                      uint2* __restrict__ ebuf) {
    const int blk = blockIdx.x;
    const int k = blk / NEB, cb = blk - k * NEB;
    __shared__ int hist[NBKT], binoff[NBKT], cur[NBKT];
    __shared__ int sc[256];
    __shared__ uint2 stage[EPB];
    const int t = threadIdx.x;
    for (int i = t; i < NBKT; i += 256) hist[i] = 0;
    __syncthreads();
    const int e0 = cb * EPB, e1 = min(e0 + EPB, NE);
    for (int e = e0 + t; e < e1; e += 256)
        atomicAdd(&hist[dst[(size_t)k * NE + e] >> 9], 1);
    __syncthreads();
    int hv = (t < NBKT) ? hist[t] : 0;
    sc[t] = hv;
    __syncthreads();
    for (int off = 1; off < 256; off <<= 1) {
        int u = (t >= off) ? sc[t - off] : 0;
        __syncthreads();
        sc[t] += u;
        __syncthreads();
    }
    if (t < NBKT) { binoff[t] = sc[t] - hv; cur[t] = sc[t] - hv; }
    __syncthreads();
    for (int e = e0 + t; e < e1; e += 256) {
        int d = dst[(size_t)k * NE + e], s = src[(size_t)k * NE + e];
        int b = d >> 9;
        int p = atomicAdd(&cur[b], 1);
        stage[p] = make_uint2((unsigned)s, (unsigned)d);
    }
    __syncthreads();
    const int n = e1 - e0;
    for (int i = t; i < n; i += 256) {
        uint2 ed = stage[i];
        int b = (int)(ed.y >> 9);
        int pos = bucketStart[k * NBKT + b] + blockBase[(size_t)blk * NBKT + b] + (i - binoff[b]);
        ebuf[pos] = ed;
    }
}

// ---- per-bucket degree histogram; also emits the two 256-node bsum entries
// (replaces scan_a) ----
__global__ void bucket_deg_kernel(const uint2* __restrict__ ebuf,
                                  const int* __restrict__ bucketStart, int* __restrict__ degi,
                                  int* __restrict__ bsum) {
    const int blk = blockIdx.x;               // KE*NBKT
    const int k = blk / NBKT, b = blk - k * NBKT;
    __shared__ int cnt[512];
    const int t = threadIdx.x;
    for (int i = t; i < 512; i += 256) cnt[i] = 0;
    __syncthreads();
    const int s0 = bucketStart[blk];
    const int s1 = (blk + 1 < KE * NBKT) ? bucketStart[blk + 1] : KE * NE;
    for (int e = s0 + t; e < s1; e += 256)
        atomicAdd(&cnt[ebuf[e].y & 511], 1);
    __syncthreads();
    const int n0 = b << 9;
    for (int i = t; i < 512; i += 256) {
        int node = n0 + i;
        if (node < NN) degi[(size_t)k * NN + node] = cnt[i];
    }
    __syncthreads();
    // destructive tree reduce: cnt[0]=sum(0..255), cnt[256]=sum(256..511)
    for (int off = 128; off > 0; off >>= 1) {
        if (t < off) { cnt[t] += cnt[t + off]; cnt[256 + t] += cnt[256 + t + off]; }
        __syncthreads();
    }
    if (t == 0) {
        bsum[k * NB + 2 * b] = cnt[0];
        if (2 * b + 1 < NB) bsum[k * NB + 2 * b + 1] = cnt[256];
    }
}

__global__ void scan_b_kernel(int* __restrict__ bsum) {
    const int k = blockIdx.x;
    const int t = threadIdx.x;          // 512
    int v = (t < NB) ? bsum[k * NB + t] : 0;
    __shared__ int sd[512];
    sd[t] = v;
    __syncthreads();
    for (int off = 1; off < 512; off <<= 1) {
        int u = (t >= off) ? sd[t - off] : 0;
        __syncthreads();
        sd[t] += u;
        __syncthreads();
    }
    if (t < NB) bsum[k * NB + t] = sd[t] - v;
}

__global__ void scan_c_kernel(const int* __restrict__ degi, const int* __restrict__ bsum,
                              int* __restrict__ rowptr, float* __restrict__ invdeg) {
    const int b = blockIdx.x;
    const int k = b / NB, lb = b - k * NB;
    const int t = threadIdx.x;
    const int i = lb * 256 + t;
    int deg = (i < NN) ? degi[(size_t)k * NN + i] : 0;
    __shared__ int sd[256];
    sd[t] = deg;
    __syncthreads();
    for (int off = 1; off < 256; off <<= 1) {
        int u = (t >= off) ? sd[t - off] : 0;
        __syncthreads();
        sd[t] += u;
        __syncthreads();
    }
    int val = bsum[b] + sd[t] - deg;
    if (i < NN) {
        rowptr[(size_t)k * (NN + 1) + i] = val;
        invdeg[(size_t)k * NN + i] = 1.0f / (float)max(deg, 1);
    }
    if (i == NN) rowptr[(size_t)k * (NN + 1) + NN] = NE;
}

__global__ void bucket_fill_kernel(const uint2* __restrict__ ebuf,
                                   const int* __restrict__ bucketStart,
                                   const int* __restrict__ rowptr, int* __restrict__ csr) {
    const int blk = blockIdx.x;
    const int k = blk / NBKT, b = blk - k * NBKT;
    __shared__ int cur[512];
    const int n0 = b << 9;
    for (int i = threadIdx.x; i < 512; i += 256) {
        int node = n0 + i;
        cur[i] = (node < NN) ? rowptr[(size_t)k * (NN + 1) + node] : 0;
    }
    __syncthreads();
    const int s0 = bucketStart[blk];
    const int s1 = (blk + 1 < KE * NBKT) ? bucketStart[blk + 1] : KE * NE;
    for (int e = s0 + threadIdx.x; e < s1; e += 256) {
        uint2 ed = ebuf[e];
        int p = atomicAdd(&cur[ed.y & 511], 1);
        csr[(size_t)k * NE + p] = (int)ed.x;
    }
}

// ---- gather (all 3 etypes), bf16 rows, 16 lanes/node, 4 edges in flight ----
// affine!=0: apply BN of previous layer post-aggregation:
//   neigh_post = sc * mean(acc_src) + (deg>0 ? sh : 0)
__global__ void gather3_kernel(const ushort* __restrict__ hsrc, const int* __restrict__ csr,
                               const int* __restrict__ rowptr, const float* __restrict__ invdeg,
                               ushort* __restrict__ neigh, const float* __restrict__ ssl,
                               int affine) {
    int g = blockIdx.x * 16 + (threadIdx.x >> 4);
    if (g >= KE * NN) return;
    int k = g / NN, node = g - k * NN;
    const int q = (threadIdx.x & 15) * 8;
    const int* rp = rowptr + (size_t)k * (NN + 1) + node;
    const int* cs = csr + (size_t)k * NE;
    int beg = rp[0], end = rp[1];
    float f0=0,f1=0,f2=0,f3=0,f4=0,f5=0,f6=0,f7=0;
    int j = beg;
    for (; j + 4 <= end; j += 4) {
        int s0 = cs[j], s1 = cs[j + 1], s2 = cs[j + 2], s3 = cs[j + 3];
        uint4 a = *(const uint4*)(hsrc + (size_t)s0 * D + q);
        uint4 b = *(const uint4*)(hsrc + (size_t)s1 * D + q);
        uint4 c = *(const uint4*)(hsrc + (size_t)s2 * D + q);
        uint4 d = *(const uint4*)(hsrc + (size_t)s3 * D + q);
        f0 += bf2f(a.x & 0xffff) + bf2f(b.x & 0xffff) + bf2f(c.x & 0xffff) + bf2f(d.x & 0xffff);
        f1 += bf2f(a.x >> 16)    + bf2f(b.x >> 16)    + bf2f(c.x >> 16)    + bf2f(d.x >> 16);
        f2 += bf2f(a.y & 0xffff) + bf2f(b.y & 0xffff) + bf2f(c.y & 0xffff) + bf2f(d.y & 0xffff);
        f3 += bf2f(a.y >> 16)    + bf2f(b.y >> 16)    + bf2f(c.y >> 16)    + bf2f(d.y >> 16);
        f4 += bf2f(a.z & 0xffff) + bf2f(b.z & 0xffff) + bf2f(c.z & 0xffff) + bf2f(d.z & 0xffff);
        f5 += bf2f(a.z >> 16)    + bf2f(b.z >> 16)    + bf2f(c.z >> 16)    + bf2f(d.z >> 16);
        f6 += bf2f(a.w & 0xffff) + bf2f(b.w & 0xffff) + bf2f(c.w & 0xffff) + bf2f(d.w & 0xffff);
        f7 += bf2f(a.w >> 16)    + bf2f(b.w >> 16)    + bf2f(c.w >> 16)    + bf2f(d.w >> 16);
    }
    for (; j < end; ++j) {
        int s0 = cs[j];
        uint4 a = *(const uint4*)(hsrc + (size_t)s0 * D + q);
        f0 += bf2f(a.x & 0xffff); f1 += bf2f(a.x >> 16);
        f2 += bf2f(a.y & 0xffff); f3 += bf2f(a.y >> 16);
        f4 += bf2f(a.z & 0xffff); f5 += bf2f(a.z >> 16);
        f6 += bf2f(a.w & 0xffff); f7 += bf2f(a.w >> 16);
    }
    float iv = invdeg[g];
    float r0 = f0 * iv, r1 = f1 * iv, r2 = f2 * iv, r3 = f3 * iv;
    float r4 = f4 * iv, r5 = f5 * iv, r6 = f6 * iv, r7 = f7 * iv;
    if (affine) {
        float4 c0 = *(const float4*)(ssl + q);
        float4 c1 = *(const float4*)(ssl + q + 4);
        float4 h0 = *(const float4*)(ssl + D + q);
        float4 h1 = *(const float4*)(ssl + D + q + 4);
        float m = (end > beg) ? 1.0f : 0.0f;   // deg==0 -> neighbor feat is exactly 0
        r0 = r0 * c0.x + m * h0.x;  r1 = r1 * c0.y + m * h0.y;
        r2 = r2 * c0.z + m * h0.z;  r3 = r3 * c0.w + m * h0.w;
        r4 = r4 * c1.x + m * h1.x;  r5 = r5 * c1.y + m * h1.y;
        r6 = r6 * c1.z + m * h1.z;  r7 = r7 * c1.w + m * h1.w;
    }
    uint4 o;
    o.x = pack2(r0, r1);
    o.y = pack2(r2, r3);
    o.z = pack2(r4, r5);
    o.w = pack2(r6, r7);
    *(uint4*)(neigh + (size_t)k * NNP * D + (size_t)node * D + q) = o;
}

// ---- fused layer GEMM + column stats; double-buffered 12-phase pipeline ----
// 512 threads / 8 waves (2Mx4N), 128-row tile, per-wave output 64x32.
// LDS: ST[2 bufs][A 16K | B 16K] = 64 KB -> 2 blocks/CU = 16 waves/CU.
// Each phase: ONE barrier -> prefetch next chunk into buf^1 -> MFMA on buf.
// Phase p: etype k=p>>2, chunk c=p&3 (c0 self/kc0, c1 self/kc1, c2 neigh/kc0, c3 neigh/kc1).
// LDS swizzle (both-sides, rule #21): stored col-chunk cc (16B) of row r holds
// global chunk cc ^ (r&7); readers XOR the same.
__global__ __launch_bounds__(512, 4)
void layer_gemm_kernel(const ushort* __restrict__ hself, const ushort* __restrict__ neigh,
                       const ushort* __restrict__ Bt,
                       const float* __restrict__ bias,
                       ushort* __restrict__ accb, int relu,
                       float* __restrict__ colsum, float* __restrict__ colsq) {
    __shared__ __align__(16) ushort ST[2][2][128][64];   // [buf][A/B][row][col] = 64 KB
    const int tid  = threadIdx.x;
    const int wave = tid >> 6, lane = tid & 63;        // 8 waves
    const int wm = wave & 1, wn = wave >> 1;           // wm 0..1 (rows), wn 0..3 (cols)
    const int lrow = lane & 15, quad = lane >> 4;
    const int m0 = blockIdx.x * 128;
    // staging geometry (gload16): lane -> row = base + (lane>>3), col chunk = lane&7
    const int srow  = lane >> 3;
    const int scolb = ((lane & 7) ^ srow) << 4;        // pre-swizzled source col byte

#define STAGE(b, kk, cc)                                                                 \
    {                                                                                    \
        const char* Asrc = ((cc) < 2) ? (const char*)hself                               \
                                      : (const char*)(neigh + (size_t)(kk) * NNP * D);   \
        const char* Bsrc = (const char*)Bt + (size_t)(kk) * 65536;                       \
        char* Adst = (char*)&ST[b][0][0][0];                                             \
        char* Bdst = (char*)&ST[b][1][0][0];                                             \
        _Pragma("unroll")                                                                \
        for (int i = 0; i < 2; ++i) {                                                    \
            int r = wave * 16 + i * 8 + srow;                                            \
            gload16(Asrc + (size_t)(m0 + r) * 256 + ((cc) & 1) * 128 + scolb,            \
                    Adst + wave * 2048 + i * 1024);                                      \
        }                                                                                \
        _Pragma("unroll")                                                                \
        for (int i = 0; i < 2; ++i) {                                                    \
            int n = wave * 16 + i * 8 + srow;                                            \
            gload16(Bsrc + (size_t)n * 512 + (cc) * 128 + scolb,                         \
                    Bdst + wave * 2048 + i * 1024);                                      \
        }                                                                                \
    }

    floatx4 tot[4][2], o4[4][2];
    #pragma unroll
    for (int a = 0; a < 4; ++a)
        #pragma unroll
        for (int b = 0; b < 2; ++b) {
            tot[a][b] = (floatx4){0.f, 0.f, 0.f, 0.f};
            o4[a][b]  = (floatx4){0.f, 0.f, 0.f, 0.f};
        }

    // prologue: stage phase 0 (etype 0, chunk 0) into buf 0
    STAGE(0, 0, 0);

    int cur = 0;
    #pragma unroll
    for (int p = 0; p < 4 * KE; ++p) {
        __syncthreads();                       // buf[cur] staged; prior reads of buf[cur^1] done
        if (p + 1 < 4 * KE) {
            const int pn = p + 1;
            STAGE(cur ^ 1, pn >> 2, pn & 3);   // prefetch next chunk (hides under MFMA)
        }
        const char* Ab = (const char*)&ST[cur][0][0][0];
        const char* Bb = (const char*)&ST[cur][1][0][0];
        #pragma unroll
        for (int ks = 0; ks < 2; ++ks) {
            short8 af[4], bfr[2];
            const int cb = ks * 64 + quad * 16;
            #pragma unroll
            for (int im = 0; im < 4; ++im) {
                int ra = wm * 64 + im * 16 + lrow;
                af[im] = *(const short8*)(Ab + ra * 128 + (cb ^ ((ra & 7) << 4)));
            }
            #pragma unroll
            for (int in = 0; in < 2; ++in) {
                int rb = wn * 32 + in * 16 + lrow;
                bfr[in] = *(const short8*)(Bb + rb * 128 + (cb ^ ((rb & 7) << 4)));
            }
            #pragma unroll
            for (int im = 0; im < 4; ++im)
                #pragma unroll
                for (int in = 0; in < 2; ++in)
                    o4[im][in] = __builtin_amdgcn_mfma_f32_16x16x32_bf16(
                        af[im], bfr[in], o4[im][in], 0, 0, 0);
        }
        if ((p & 3) == 3) {                    // etype complete: bias + relu + accumulate
            const float* bk = bias + (p >> 2) * D;
            float bv[2];
            #pragma unroll
            for (int in = 0; in < 2; ++in) bv[in] = bk[wn * 32 + in * 16 + lrow];
            #pragma unroll
            for (int im = 0; im < 4; ++im)
                #pragma unroll
                for (int in = 0; in < 2; ++in)
                    #pragma unroll
                    for (int r = 0; r < 4; ++r) {
                        float v = o4[im][in][r] + bv[in];
                        if (relu) v = fmaxf(v, 0.f);
                        tot[im][in][r] += v;
                        o4[im][in][r] = 0.f;
                    }
        }
        cur ^= 1;
    }
#undef STAGE

    // ---- fused column stats from fp32 registers (mask tail rows >= NN) ----
    float ls[2] = {0.f, 0.f}, lq[2] = {0.f, 0.f};
    #pragma unroll
    for (int im = 0; im < 4; ++im)
        #pragma unroll
        for (int r = 0; r < 4; ++r) {
            int row = m0 + wm * 64 + im * 16 + quad * 4 + r;
            bool ok = row < NN;
            #pragma unroll
            for (int in = 0; in < 2; ++in) {
                float v = ok ? tot[im][in][r] : 0.f;
                ls[in] += v;
                lq[in] += v * v;
            }
        }
    __syncthreads();                                   // all MFMA LDS reads done
    float* redS = (float*)&ST[1][0][0][0];             // [128][8] floats (8 KB, in buf1-A)
    float* redQ = redS + 1024;
    #pragma unroll
    for (int in = 0; in < 2; ++in) {
        int col = wn * 32 + in * 16 + lrow;
        int slot = col * 8 + wm * 4 + quad;            // (wm,quad) unique per col
        redS[slot] = ls[in];
        redQ[slot] = lq[in];
    }
    __syncthreads();
    if (tid < 128) {
        float s = 0.f, q = 0.f;
        #pragma unroll
        for (int i = 0; i < 8; ++i) { s += redS[tid * 8 + i]; q += redQ[tid * 8 + i]; }
        int slice = blockIdx.x & (NSL - 1);
        atomic_add_f32(&colsum[slice * D + tid], s);
        atomic_add_f32(&colsq[slice * D + tid], q);
    }

    // ---- C tile -> LDS (bf16, buf0 region = 32 KB; disjoint from redS/redQ) ----
    ushort* Cs = &ST[0][0][0][0];                      // [128][128] ushort = 32 KB
    #pragma unroll
    for (int im = 0; im < 4; ++im)
        #pragma unroll
        for (int r = 0; r < 4; ++r) {
            int rl = wm * 64 + im * 16 + quad * 4 + r;
            #pragma unroll
            for (int in = 0; in < 2; ++in)
                Cs[rl * 128 + wn * 32 + in * 16 + lrow] = (ushort)f2bf(tot[im][in][r]);
        }
    __syncthreads();
    #pragma unroll
    for (int jj = 0; jj < 4; ++jj) {
        int c8 = tid + jj * 512;           // uint4 index, 2048 total
        int rl = c8 >> 4;                  // 16 uint4 per 128-col row
        int cc = (c8 & 15) * 8;
        int row = m0 + rl;
        if (row < NN)
            *(uint4*)(accb + (size_t)row * D + cc) = *(const uint4*)(Cs + rl * 128 + cc);
    }
}

// ---- batchnorm finalize (last layer only; stats zeroed upfront by wprep) ----
__global__ void finalize_kernel(const float* __restrict__ colsum, const float* __restrict__ colsq,
                                const float* __restrict__ gamma, const float* __restrict__ beta,
                                float* __restrict__ ssl) {
    int c = threadIdx.x;  // 128
    float s = 0.f, q = 0.f;
    #pragma unroll
    for (int i = 0; i < NSL; ++i) { s += colsum[i * D + c]; q += colsq[i * D + c]; }
    float mu  = s * (1.0f / NN);
    float var = q * (1.0f / NN) - mu * mu;
    float sc  = gamma[c] * rsqrtf(var + EPS);
    ssl[c]     = sc;
    ssl[D + c] = beta[c] - mu * sc;
}

// ---- final BN apply (fp32 out), only for the last layer ----
__global__ void bn_kernel(const ushort* __restrict__ accb, const float* __restrict__ ssl,
                          float* __restrict__ out) {
    size_t i = (size_t)blockIdx.x * blockDim.x + threadIdx.x;
    if (i >= (size_t)NN * D / 4) return;
    int c4 = (int)(i & 31) << 2;
    uint2 a = *(const uint2*)(accb + i * 4);
    float4 v = {bf2f(a.x & 0xffff), bf2f(a.x >> 16), bf2f(a.y & 0xffff), bf2f(a.y >> 16)};
    float4 sc = *(const float4*)(ssl + c4);
    float4 sh = *(const float4*)(ssl + D + c4);
    float4 o;
    o.x = v.x * sc.x + sh.x;
    o.y = v.y * sc.y + sh.y;
    o.z = v.z * sc.z + sh.z;
    o.w = v.w * sc.w + sh.w;
    *(float4*)(out + i * 4) = o;
}

extern "C" void kernel_launch(void* const* d_in, const int* in_sizes, int n_in,
                              void* d_out, int out_size, void* d_ws, size_t ws_size,
                              hipStream_t stream) {
    const float* x       = (const float*)d_in[0];
    const int*   src     = (const int*)d_in[1];
    const int*   dst     = (const int*)d_in[2];
    const float* W_self  = (const float*)d_in[3];
    const float* W_neigh = (const float*)d_in[4];
    const float* bvec    = (const float*)d_in[5];
    const float* gamma   = (const float*)d_in[6];
    const float* beta    = (const float*)d_in[7];
    float* out = (float*)d_out;

    // ---- workspace layout ----
    ushort* accb   = (ushort*)d_ws;                       // NNP*D bf16 (pre-BN activations)
    float*  invdeg = (float*)(accb + (size_t)NNP * D);    // KE*NN
    float*  colsum = invdeg + (size_t)KE * NN;            // NL*NSL*D (per-layer slices)
    float*  colsq  = colsum + NL * NSL * D;               // NL*NSL*D
    float*  ss     = colsq + NL * NSL * D;                // NL*2*D (per-layer BN affine)
    float*  biasW  = ss + NL * 2 * D;                     // KE*D (folded bias)
    ushort* hbf    = (ushort*)(biasW + KE * D);           // NNP*D bf16 (x only)
    ushort* neigh  = hbf + (size_t)NNP * D;               // KE*NNP*D bf16
    ushort* Btw    = neigh + (size_t)KE * NNP * D;        // NL*KE*128*256 bf16
    int*    degi   = (int*)(Btw + (size_t)NL * KE * 128 * 256);  // KE*NN
    int*    rowptr = degi + (size_t)KE * NN;              // KE*(NN+1)
    int*    csr    = rowptr + (size_t)KE * (NN + 1);      // KE*NE
    int*    bsum   = csr + (size_t)KE * NE;               // KE*NB
    int*    bucketTotal = bsum + (size_t)KE * NB;         // KE*NBKT
    int*    bucketStart = bucketTotal + KE * NBKT;        // KE*NBKT
    int*    blockBase   = bucketStart + KE * NBKT;        // KE*NEB*NBKT
    uint2*  ebuf   = (uint2*)accb;  // aliases accb (14.4MB <= 25.6MB); CSR build precedes layer loop

    convert_x_kernel<<<(int)(((size_t)NN * D / 4 + 255) / 256), 256, 0, stream>>>(
        x, hbf, bucketTotal);
    wprep_kernel<<<(NL * KE * 128 * 256 + 255) / 256, 256, 0, stream>>>(
        W_self, W_neigh, Btw, colsum);

    bucket_count_kernel<<<KE * NEB, 256, 0, stream>>>(dst, bucketTotal, blockBase);
    bucket_scan_kernel<<<1, 1024, 0, stream>>>(bucketTotal, bucketStart);
    bucket_scatter_kernel<<<KE * NEB, 256, 0, stream>>>(src, dst, bucketStart, blockBase, ebuf);
    bucket_deg_kernel<<<KE * NBKT, 256, 0, stream>>>(ebuf, bucketStart, degi, bsum);
    scan_b_kernel<<<KE, 512, 0, stream>>>(bsum);
    scan_c_kernel<<<KE * NB, 256, 0, stream>>>(degi, bsum, rowptr, invdeg);
    bucket_fill_kernel<<<KE * NBKT, 256, 0, stream>>>(ebuf, bucketStart, rowptr, csr);

    for (int l = 0; l < NL; ++l) {
        int relu = (l < NL - 1) ? 1 : 0;
        const ushort* hsrc = (l == 0) ? hbf : accb;      // accb = pre-BN acts of layer l-1
        const float*  ssl  = ss + (size_t)(l ? l - 1 : 0) * 2 * D;
        gather3_kernel<<<(KE * NN + 15) / 16, 256, 0, stream>>>(
            hsrc, csr, rowptr, invdeg, neigh, ssl, l > 0);
        layer_gemm_kernel<<<NNP / 128, 512, 0, stream>>>(
            hsrc, neigh,
            Btw + (size_t)l * KE * 128 * 256,
            (l == 0) ? bvec : biasW,
            accb, relu,
            colsum + (size_t)l * NSL * D, colsq + (size_t)l * NSL * D);
        if (l + 1 < NL) {
            finfold_kernel<<<KE, 128, 0, stream>>>(
                colsum + (size_t)l * NSL * D, colsq + (size_t)l * NSL * D,
                gamma + (size_t)l * D, beta + (size_t)l * D,
                W_self + (size_t)(l + 1) * KE * D * D,
                bvec + (size_t)(l + 1) * KE * D,
                ss + (size_t)l * 2 * D,
                Btw + (size_t)(l + 1) * KE * 128 * 256,
                biasW);
        } else {
            finalize_kernel<<<1, 128, 0, stream>>>(
                colsum + (size_t)l * NSL * D, colsq + (size_t)l * NSL * D,
                gamma + (size_t)l * D, beta + (size_t)l * D, ss + (size_t)l * 2 * D);
        }
    }
    bn_kernel<<<(int)(((size_t)NN * D / 4 + 255) / 256), 256, 0, stream>>>(
        accb, ss + (size_t)(NL - 1) * 2 * D, out);
}